// Round 2
// baseline (252.566 us; speedup 1.0000x reference)
//
#include <hip/hip_runtime.h>
#include <hip/hip_cooperative_groups.h>
#include <stdint.h>
#include <math.h>

namespace cg = cooperative_groups;

#define NPIX   16384
#define SAMPLE 1024
#define NV     778
#define BATCH  64

#define A_SCALE (1.0f / (float)(BATCH * SAMPLE))
#define B_SCALE (1.0f / (float)(BATCH * NV))

// Workspace layout (bytes)
#define WS_PCL    0u              // 64*1024*16  = 1048576
#define WS_HISTP  1048576u        // 256*512*4   = 524288
#define WS_CAND   1572864u        // 64*512*8    = 262144
#define WS_CANDRV 1835008u        // 64*512*4    = 131072
#define WS_CNT    1966080u        // 64*4        = 256
#define WS_CCNT   1966336u        // 64*4        = 256
#define WS_NEEDED 1966592u

// ---------------------------------------------------------------------------
// Threefry-2x32, 20 rounds — matches jax._src.prng lowering exactly.
// ---------------------------------------------------------------------------
__device__ __forceinline__ uint32_t rotl32(uint32_t v, int r) {
  return (v << r) | (v >> (32 - r));
}

__device__ __forceinline__ uint32_t threefry_bits(uint32_t g) {
  // key(1) = (0,1); partitionable path: x0 = counts_hi = 0, x1 = g; out h0^h1.
  uint32_t ks0 = 0u, ks1 = 1u;
  uint32_t ks2 = ks0 ^ ks1 ^ 0x1BD11BDAu;
  uint32_t x0 = 0u + ks0, x1 = g + ks1;
#define TF_R(r) { x0 += x1; x1 = rotl32(x1, (r)); x1 ^= x0; }
  TF_R(13) TF_R(15) TF_R(26) TF_R(6)
  x0 += ks1; x1 += ks2 + 1u;
  TF_R(17) TF_R(29) TF_R(16) TF_R(24)
  x0 += ks2; x1 += ks0 + 2u;
  TF_R(13) TF_R(15) TF_R(26) TF_R(6)
  x0 += ks0; x1 += ks1 + 3u;
  TF_R(17) TF_R(29) TF_R(16) TF_R(24)
  x0 += ks1; x1 += ks2 + 4u;
  TF_R(13) TF_R(15) TF_R(26) TF_R(6)
  x0 += ks2; x1 += ks0 + 5u;
#undef TF_R
  return x0 ^ x1;
}

__device__ __forceinline__ float waveReduceSum(float v) {
#pragma unroll
  for (int off = 32; off > 0; off >>= 1) v += __shfl_down(v, off, 64);
  return v;
}

// ---------------------------------------------------------------------------
// Fused cooperative kernel: 256 blocks x 1024 threads; block = (batch, quarter).
// Phase 1: threefry score (u-bits in regs), LDS hist -> global partial hist.
// Phase 2: sum partials, suffix scan, bstar/kneed; ballot-compact own pixels
//          via per-batch global atomic counters.  Phase 3 (q==0): rank-select
//          boundary bucket.  Phase 4: chamfer (A: point-slice x all verts,
//          B: vert-slice x all points; wave-uniform LDS broadcasts).
// ---------------------------------------------------------------------------
__global__ __launch_bounds__(1024) void fused_kernel(
    const float4* __restrict__ real4,
    const float* __restrict__ verts,
    const float* __restrict__ center,
    const float* __restrict__ M,
    const float* __restrict__ cube,
    float* __restrict__ out,
    float4* __restrict__ pcl4,
    uint32_t* __restrict__ histp,
    uint64_t* __restrict__ candg,
    float* __restrict__ candrvg,
    uint32_t* __restrict__ cnts,
    uint32_t* __restrict__ ccnts) {
  cg::grid_group grid = cg::this_grid();
  const int bq = blockIdx.x;
  const int b = bq >> 2, q = bq & 3;
  const int tid = threadIdx.x;
  const int lane = tid & 63;
  const int wv = tid >> 6;

  __shared__ __align__(16) uint8_t shbuf[45216];
  __shared__ uint32_t wt[8], offs[8];
  __shared__ float sh_minv[6], sh_c[3], sh_hb[3];
  __shared__ uint32_t sh_bstar, sh_above;
  __shared__ float red[16];

  uint32_t* hist = (uint32_t*)shbuf;

  // ---- Phase 1: score ----
  if (bq == 0 && tid == 0) out[0] = 0.0f;
  if (q == 0 && tid == 0) { cnts[b] = 0u; ccnts[b] = 0u; }
  if (tid == 0) {
    const float* m = M + (size_t)b * 9;
    float m00=m[0], m01=m[1], m02=m[2];
    float m10=m[3], m11=m[4], m12=m[5];
    float m20=m[6], m21=m[7], m22=m[8];
    float c00 = m11*m22 - m12*m21;
    float c10 = m12*m20 - m10*m22;
    float c20 = m10*m21 - m11*m20;
    float det = m00*c00 + m01*c10 + m02*c20;
    float id = 1.0f / det;
    sh_minv[0] = c00 * id;
    sh_minv[1] = (m02*m21 - m01*m22) * id;
    sh_minv[2] = (m01*m12 - m02*m11) * id;
    sh_minv[3] = c10 * id;
    sh_minv[4] = (m00*m22 - m02*m20) * id;
    sh_minv[5] = (m02*m10 - m00*m12) * id;
    sh_c[0] = center[b*3+0]; sh_c[1] = center[b*3+1]; sh_c[2] = center[b*3+2];
    sh_hb[0] = cube[b*3+0]*0.5f; sh_hb[1] = cube[b*3+1]*0.5f; sh_hb[2] = cube[b*3+2]*0.5f;
  }
  if (tid < 512) hist[tid] = 0u;

  float4 im = real4[(size_t)b * 4096 + q * 1024 + tid];
  uint32_t base = (uint32_t)(b * NPIX + q * 4096) + (uint32_t)(tid << 2);
  uint32_t uvr[4]; float rvr[4];
  rvr[0] = im.x; rvr[1] = im.y; rvr[2] = im.z; rvr[3] = im.w;
  uvr[0] = (im.x <= 0.99f) ? ((threefry_bits(base + 0u) >> 9) + 1u) : 0u;
  uvr[1] = (im.y <= 0.99f) ? ((threefry_bits(base + 1u) >> 9) + 1u) : 0u;
  uvr[2] = (im.z <= 0.99f) ? ((threefry_bits(base + 2u) >> 9) + 1u) : 0u;
  uvr[3] = (im.w <= 0.99f) ? ((threefry_bits(base + 3u) >> 9) + 1u) : 0u;
  __syncthreads();
#pragma unroll
  for (int c = 0; c < 4; ++c)
    if (uvr[c]) atomicAdd(&hist[(uvr[c] - 1u) >> 14], 1u);
  __syncthreads();
  if (tid < 512) histp[(size_t)bq * 512 + tid] = hist[tid];

  grid.sync();

  // ---- Phase 2: scan + compact ----
  uint32_t cnt = 0, sfx = 0;
  if (tid < 512) {
    const uint32_t* hp = histp + (size_t)(b << 2) * 512 + tid;
    cnt = hp[0] + hp[512] + hp[1024] + hp[1536];
    sfx = cnt;
#pragma unroll
    for (int off = 1; off < 64; off <<= 1) {
      uint32_t u = __shfl_down(sfx, off, 64);
      if (lane + off < 64) sfx += u;
    }
    if (lane == 0) wt[wv] = sfx;
  }
  __syncthreads();
  if (tid < 8) {
    uint32_t t = wt[tid], s = t;
#pragma unroll
    for (int off = 1; off < 8; off <<= 1) {
      uint32_t u = __shfl_down(s, off, 64);
      if (tid + off < 8) s += u;
    }
    offs[tid] = s - t;
  }
  __syncthreads();
  if (tid < 512) {
    uint32_t tot = sfx + offs[wv];   // keys in buckets >= tid
    uint32_t above = tot - cnt;      // keys in buckets >  tid
    if (tot >= SAMPLE && above < SAMPLE && cnt > 0) {
      sh_bstar = (uint32_t)tid;
      sh_above = above;
    }
  }
  __syncthreads();
  const int bstar = (int)sh_bstar;
  const uint32_t kneed = SAMPLE - sh_above;

  float4* ob = pcl4 + (size_t)b * SAMPLE;
  auto emit = [&](int p, float depth01, uint32_t slot) {
    int i = p >> 7, j = p & 127;
    float tj = (2.0f * (float)j) / 127.0f - 1.0f;
    float ti = (2.0f * (float)i) / 127.0f - 1.0f;
    float u0 = (tj + 1.0f) * 64.0f;
    float u1 = (ti + 1.0f) * 64.0f;
    float d  = depth01 * sh_hb[2] + sh_c[2];
    float w0 = sh_minv[0]*u0 + sh_minv[1]*u1 + sh_minv[2];
    float w1 = sh_minv[3]*u0 + sh_minv[4]*u1 + sh_minv[5];
    float x = (w0 - 320.0f) * d / 588.03f;
    float y = (w1 - 240.0f) * d / 587.07f;
    float4 o;
    o.x = (x - sh_c[0]) / sh_hb[0];
    o.y = (y - sh_c[1]) / sh_hb[1];
    o.z = (d - sh_c[2]) / sh_hb[2];
    o.w = 0.0f;
    ob[slot] = o;
  };

  uint64_t* cb_ = candg + (size_t)b * 512;
  float*    crv_ = candrvg + (size_t)b * 512;
#pragma unroll
  for (int c = 0; c < 4; ++c) {
    uint32_t v = uvr[c];
    int p = q * 4096 + (tid << 2) + c;
    int bk = v ? (int)((v - 1u) >> 14) : -1;
    bool hi = (bk > bstar);
    unsigned long long m = __ballot(hi);
    if (m) {
      int leader = __ffsll((unsigned long long)m) - 1;
      uint32_t bslot;
      if (lane == leader) bslot = atomicAdd(&cnts[b], (uint32_t)__popcll(m));
      bslot = __shfl(bslot, leader, 64);
      if (hi) emit(p, rvr[c], bslot + (uint32_t)__popcll(m & ((1ull << lane) - 1ull)));
    }
    bool eqb = (bk == bstar);
    unsigned long long m2 = __ballot(eqb);
    if (m2) {
      int leader = __ffsll((unsigned long long)m2) - 1;
      uint32_t cb;
      if (lane == leader) cb = atomicAdd(&ccnts[b], (uint32_t)__popcll(m2));
      cb = __shfl(cb, leader, 64);
      if (eqb) {
        uint32_t ci = cb + (uint32_t)__popcll(m2 & ((1ull << lane) - 1ull));
        if (ci < 512) {
          cb_[ci] = ((uint64_t)v << 14) | (uint64_t)(16383 - p);
          crv_[ci] = rvr[c];
        }
      }
    }
  }

  grid.sync();

  // ---- Phase 3: boundary-bucket rank-select (one block per batch) ----
  if (q == 0) {
    uint32_t c = ccnts[b]; if (c > 512u) c = 512u;
    if (tid < 64) {
      for (uint32_t basei = 0; basei < c; basei += 64) {
        uint32_t i = basei + (uint32_t)lane;
        bool act = (i < c);
        uint64_t ki = act ? cb_[i] : 0ull;
        uint32_t rank = 0;
        for (uint32_t j2 = 0; j2 < c; ++j2) rank += (cb_[j2] > ki) ? 1u : 0u;
        bool sel = act && (rank < kneed);   // keys unique -> exactly kneed
        unsigned long long m = __ballot(sel);
        if (m) {
          int leader = __ffsll((unsigned long long)m) - 1;
          uint32_t bslot;
          if (lane == leader) bslot = atomicAdd(&cnts[b], (uint32_t)__popcll(m));
          bslot = __shfl(bslot, leader, 64);
          if (sel) {
            int p = 16383 - (int)(ki & 0x3FFFull);
            emit(p, crv_[i], bslot + (uint32_t)__popcll(m & ((1ull << lane) - 1ull)));
          }
        }
      }
    }
  }

  grid.sync();

  // ---- Phase 4: chamfer ----
  // LDS: sv4[778] staged verts (12448 B) | sp4[1024] staged points (16384 B)
  //      | fbuf[16][256] float partial-min (16384 B)
  float4* sv4 = (float4*)shbuf;
  float4* sp4 = (float4*)(shbuf + 12448);
  float*  fbuf = (float*)(shbuf + 28832);

  const float* vb = verts + (size_t)b * NV * 3;
  if (tid < NV) {
    float x = vb[tid*3], y = vb[tid*3+1], z = vb[tid*3+2];
    float4 t;
    t.x = -2.0f*x; t.y = -2.0f*y; t.z = -2.0f*z; t.w = x*x + y*y + z*z;
    sv4[tid] = t;
  }
  {
    float4 qd = ob[tid];
    float4 t;
    t.x = -2.0f*qd.x; t.y = -2.0f*qd.y; t.z = -2.0f*qd.z;
    t.w = qd.x*qd.x + qd.y*qd.y + qd.z*qd.z;
    sp4[tid] = t;
  }
  __syncthreads();

  float val = 0.0f;
  const int sub = tid & 63;   // lane within wave (wave-uniform segment id below)
  const int seg16 = tid >> 6; // 0..15, constant within a wave

  // dir A: points q*256..q*256+255 (this block's slice) vs ALL verts.
  // 16-way vert split (wave-uniform) x 4 points/thread.
  {
    float px[4], py[4], pz[4], mnA[4];
#pragma unroll
    for (int j = 0; j < 4; ++j) {
      float4 sp = sp4[q * 256 + j * 64 + sub];
      px[j] = -0.5f * sp.x; py[j] = -0.5f * sp.y; pz[j] = -0.5f * sp.z;
      mnA[j] = INFINITY;
    }
    int vs = seg16 * 49, ve = vs + 49; if (ve > NV) ve = NV;
    for (int v = vs; v < ve; ++v) {
      float4 vv = sv4[v];                       // wave-uniform broadcast
#pragma unroll
      for (int j = 0; j < 4; ++j) {
        float t = fmaf(pz[j], vv.z, fmaf(py[j], vv.y, fmaf(px[j], vv.x, vv.w)));
        mnA[j] = fminf(mnA[j], t);
      }
    }
#pragma unroll
    for (int j = 0; j < 4; ++j) fbuf[seg16 * 256 + j * 64 + sub] = mnA[j];
  }
  __syncthreads();
  if (tid < 256) {
    float m = fbuf[tid];
#pragma unroll
    for (int s2 = 1; s2 < 16; ++s2) m = fminf(m, fbuf[s2 * 256 + tid]);
    val += (m + sp4[q * 256 + tid].w) * A_SCALE;
  }
  __syncthreads();

  // dir B: verts q*195..q*195+nsl (this block's slice) vs ALL points.
  // 16-way point split (wave-uniform) x 4 verts/thread.
  {
    const int vbase = q * 195;
    int nsl = NV - vbase; if (nsl > 195) nsl = 195;
    float vx[4], vy[4], vz[4], mnB[4];
#pragma unroll
    for (int j = 0; j < 4; ++j) {
      int vloc = j * 64 + sub;
      int vi = (vloc < nsl) ? (vbase + vloc) : 0;
      float4 sv = sv4[vi];
      vx[j] = -0.5f * sv.x; vy[j] = -0.5f * sv.y; vz[j] = -0.5f * sv.z;
      mnB[j] = INFINITY;
    }
    int is = seg16 * 64;
    for (int i = 0; i < 64; ++i) {
      float4 pp = sp4[is + i];                  // wave-uniform broadcast
#pragma unroll
      for (int j = 0; j < 4; ++j) {
        float t = fmaf(vz[j], pp.z, fmaf(vy[j], pp.y, fmaf(vx[j], pp.x, pp.w)));
        mnB[j] = fminf(mnB[j], t);
      }
    }
#pragma unroll
    for (int j = 0; j < 4; ++j) fbuf[seg16 * 256 + j * 64 + sub] = mnB[j];
  }
  __syncthreads();
  {
    const int vbase = q * 195;
    int nsl = NV - vbase; if (nsl > 195) nsl = 195;
    if (tid < nsl) {
      float m = fbuf[tid];
#pragma unroll
      for (int s2 = 1; s2 < 16; ++s2) m = fminf(m, fbuf[s2 * 256 + tid]);
      val += (m + sv4[vbase + tid].w) * B_SCALE;
    }
  }

  float r = waveReduceSum(val);
  if (lane == 0) red[wv] = r;
  __syncthreads();
  if (tid == 0) {
    float s = 0.0f;
#pragma unroll
    for (int i = 0; i < 16; ++i) s += red[i];
    atomicAdd(out, s);
  }
}

// ===========================================================================
// Fallback path (verified round-0 kernels, unchanged).
// ===========================================================================
__global__ __launch_bounds__(1024) void select_kernel(
    const float4* __restrict__ real4,
    const float* __restrict__ center,
    const float* __restrict__ M,
    const float* __restrict__ cube,
    float4* __restrict__ pcl4,
    float* __restrict__ out) {
  const int b = blockIdx.x;
  const int tid = threadIdx.x;
  const int lane = tid & 63;
  const int wv = tid >> 6;

  if (b == 0 && tid == 0) out[0] = 0.0f;

  __shared__ uint32_t hist[512];
  __shared__ uint32_t wt[8], offs[8];
  __shared__ uint64_t cand[512];
  __shared__ float candrv[512];
  __shared__ float sh_minv[6], sh_c[3], sh_hb[3];
  __shared__ uint32_t sh_cnt, sh_ccnt, sh_bstar, sh_above;

  if (tid == 0) {
    const float* m = M + (size_t)b * 9;
    float m00=m[0], m01=m[1], m02=m[2];
    float m10=m[3], m11=m[4], m12=m[5];
    float m20=m[6], m21=m[7], m22=m[8];
    float c00 = m11*m22 - m12*m21;
    float c10 = m12*m20 - m10*m22;
    float c20 = m10*m21 - m11*m20;
    float det = m00*c00 + m01*c10 + m02*c20;
    float id = 1.0f / det;
    sh_minv[0] = c00 * id;
    sh_minv[1] = (m02*m21 - m01*m22) * id;
    sh_minv[2] = (m01*m12 - m02*m11) * id;
    sh_minv[3] = c10 * id;
    sh_minv[4] = (m00*m22 - m02*m20) * id;
    sh_minv[5] = (m02*m10 - m00*m12) * id;
    sh_c[0] = center[b*3+0]; sh_c[1] = center[b*3+1]; sh_c[2] = center[b*3+2];
    sh_hb[0] = cube[b*3+0]*0.5f; sh_hb[1] = cube[b*3+1]*0.5f; sh_hb[2] = cube[b*3+2]*0.5f;
    sh_cnt = 0; sh_ccnt = 0;
  }
  if (tid < 512) hist[tid] = 0;

  uint32_t uv[16];
  float    rv[16];
  const float4* rb4 = real4 + (size_t)b * (NPIX / 4);
#pragma unroll
  for (int e4 = 0; e4 < 4; ++e4) {
    float4 im = rb4[e4 * 1024 + tid];
    uint32_t base = (uint32_t)(b * NPIX + e4 * 4096) + (uint32_t)(tid << 2);
    rv[e4*4+0] = im.x; rv[e4*4+1] = im.y; rv[e4*4+2] = im.z; rv[e4*4+3] = im.w;
    uv[e4*4+0] = (im.x <= 0.99f) ? ((threefry_bits(base + 0u) >> 9) + 1u) : 0u;
    uv[e4*4+1] = (im.y <= 0.99f) ? ((threefry_bits(base + 1u) >> 9) + 1u) : 0u;
    uv[e4*4+2] = (im.z <= 0.99f) ? ((threefry_bits(base + 2u) >> 9) + 1u) : 0u;
    uv[e4*4+3] = (im.w <= 0.99f) ? ((threefry_bits(base + 3u) >> 9) + 1u) : 0u;
  }
  __syncthreads();

#pragma unroll
  for (int e = 0; e < 16; ++e)
    if (uv[e]) atomicAdd(&hist[(uv[e] - 1u) >> 14], 1u);
  __syncthreads();

  uint32_t cnt = 0, sfx = 0;
  if (tid < 512) {
    cnt = hist[tid];
    sfx = cnt;
#pragma unroll
    for (int off = 1; off < 64; off <<= 1) {
      uint32_t u = __shfl_down(sfx, off, 64);
      if (lane + off < 64) sfx += u;
    }
    if (lane == 0) wt[wv] = sfx;
  }
  __syncthreads();
  if (tid < 8) {
    uint32_t t = wt[tid], s = t;
#pragma unroll
    for (int off = 1; off < 8; off <<= 1) {
      uint32_t u = __shfl_down(s, off, 64);
      if (tid + off < 8) s += u;
    }
    offs[tid] = s - t;
  }
  __syncthreads();
  if (tid < 512) {
    uint32_t tot = sfx + offs[wv];
    uint32_t above = tot - cnt;
    if (tot >= SAMPLE && above < SAMPLE && cnt > 0) {
      sh_bstar = (uint32_t)tid;
      sh_above = above;
    }
  }
  __syncthreads();
  const int bstar = (int)sh_bstar;
  const uint32_t kneed = SAMPLE - sh_above;

  float4* ob = pcl4 + (size_t)b * SAMPLE;
  auto emit = [&](int p, float depth01, uint32_t slot) {
    int i = p >> 7, j = p & 127;
    float tj = (2.0f * (float)j) / 127.0f - 1.0f;
    float ti = (2.0f * (float)i) / 127.0f - 1.0f;
    float u0 = (tj + 1.0f) * 64.0f;
    float u1 = (ti + 1.0f) * 64.0f;
    float d  = depth01 * sh_hb[2] + sh_c[2];
    float w0 = sh_minv[0]*u0 + sh_minv[1]*u1 + sh_minv[2];
    float w1 = sh_minv[3]*u0 + sh_minv[4]*u1 + sh_minv[5];
    float x = (w0 - 320.0f) * d / 588.03f;
    float y = (w1 - 240.0f) * d / 587.07f;
    float4 o;
    o.x = (x - sh_c[0]) / sh_hb[0];
    o.y = (y - sh_c[1]) / sh_hb[1];
    o.z = (d - sh_c[2]) / sh_hb[2];
    o.w = 0.0f;
    ob[slot] = o;
  };

#pragma unroll
  for (int e = 0; e < 16; ++e) {
    uint32_t v = uv[e];
    int p = (e >> 2) * 4096 + (tid << 2) + (e & 3);
    int bk = v ? (int)((v - 1u) >> 14) : -1;
    bool hi = (bk > bstar);
    unsigned long long m = __ballot(hi);
    if (m) {
      int leader = __ffsll((unsigned long long)m) - 1;
      uint32_t base;
      if (lane == leader) base = atomicAdd(&sh_cnt, (uint32_t)__popcll(m));
      base = __shfl(base, leader, 64);
      if (hi) emit(p, rv[e], base + (uint32_t)__popcll(m & ((1ull << lane) - 1ull)));
    }
    bool eqb = (bk == bstar);
    unsigned long long m2 = __ballot(eqb);
    if (m2) {
      int leader = __ffsll((unsigned long long)m2) - 1;
      uint32_t cb;
      if (lane == leader) cb = atomicAdd(&sh_ccnt, (uint32_t)__popcll(m2));
      cb = __shfl(cb, leader, 64);
      if (eqb) {
        uint32_t ci = cb + (uint32_t)__popcll(m2 & ((1ull << lane) - 1ull));
        if (ci < 512) {
          cand[ci] = ((uint64_t)v << 14) | (uint64_t)(16383 - p);
          candrv[ci] = rv[e];
        }
      }
    }
  }
  __syncthreads();

  uint32_t c = sh_ccnt; if (c > 512) c = 512;
  if (tid < 64) {
    for (uint32_t basei = 0; basei < c; basei += 64) {
      uint32_t i = basei + (uint32_t)lane;
      bool act = (i < c);
      uint64_t ki = act ? cand[i] : 0ull;
      uint32_t rank = 0;
      for (uint32_t j2 = 0; j2 < c; ++j2) rank += (cand[j2] > ki) ? 1u : 0u;
      bool sel = act && (rank < kneed);
      unsigned long long m = __ballot(sel);
      if (m) {
        int leader = __ffsll((unsigned long long)m) - 1;
        uint32_t base;
        if (lane == leader) base = atomicAdd(&sh_cnt, (uint32_t)__popcll(m));
        base = __shfl(base, leader, 64);
        if (sel) {
          int p = 16383 - (int)(ki & 0x3FFFull);
          emit(p, candrv[i], base + (uint32_t)__popcll(m & ((1ull << lane) - 1ull)));
        }
      }
    }
  }
}

#define NA_BLOCKS 512
#define NB_SLICES 7
#define NB_BLOCKS (BATCH * NB_SLICES)

__global__ __launch_bounds__(256, 4) void dist_kernel(
    const float* __restrict__ verts,
    const float4* __restrict__ pcl4,
    float* __restrict__ out) {
  __shared__ __align__(16) uint8_t shbuf[20992];
  __shared__ float red[4];
  const int blk = blockIdx.x;
  const int tid = threadIdx.x;
  const int s = tid >> 5;
  const int g = tid & 31;
  float val = 0.0f;

  if (blk < NA_BLOCKS) {
    const int b = blk >> 3, slice = blk & 7;
    float4* sv4 = (float4*)shbuf;
    float* pmin = (float*)(shbuf + 12448);
    float* npl  = (float*)(shbuf + 16544);
    const float* vb = verts + (size_t)b * NV * 3;
    for (int v = tid; v < NV; v += 256) {
      float x = vb[v*3], y = vb[v*3+1], z = vb[v*3+2];
      float4 t;
      t.x = -2.0f*x; t.y = -2.0f*y; t.z = -2.0f*z; t.w = x*x + y*y + z*z;
      sv4[v] = t;
    }
    const float4* pb = pcl4 + (size_t)b * SAMPLE + slice * 128;
    float px[4], py[4], pz[4], np[4], mn[4];
#pragma unroll
    for (int j = 0; j < 4; ++j) {
      float4 q = pb[j * 32 + g];
      px[j] = q.x; py[j] = q.y; pz[j] = q.z;
      np[j] = q.x*q.x + q.y*q.y + q.z*q.z;
      mn[j] = INFINITY;
    }
    __syncthreads();
    const int vs = s * 98;
    const int ve = (vs + 98 < NV) ? vs + 98 : NV;
    for (int v = vs; v < ve; ++v) {
      float4 vv = sv4[v];
#pragma unroll
      for (int j = 0; j < 4; ++j) {
        float t = fmaf(pz[j], vv.z, fmaf(py[j], vv.y, fmaf(px[j], vv.x, vv.w)));
        mn[j] = fminf(mn[j], t);
      }
    }
#pragma unroll
    for (int j = 0; j < 4; ++j) {
      pmin[s * 128 + j * 32 + g] = mn[j];
      if (s == 0) npl[j * 32 + g] = np[j];
    }
    __syncthreads();
    if (tid < 128) {
      float m = pmin[tid];
#pragma unroll
      for (int ss = 1; ss < 8; ++ss) m = fminf(m, pmin[ss * 128 + tid]);
      val = (m + npl[tid]) * A_SCALE;
    }
  } else {
    const int bb = blk - NA_BLOCKS;
    const int b = bb / NB_SLICES, slice = bb % NB_SLICES;
    float4* sp4 = (float4*)shbuf;
    float* vmin = (float*)(shbuf + 16384);
    float* nvl  = (float*)(shbuf + 20480);
    const float4* pcb = pcl4 + (size_t)b * SAMPLE;
    for (int i = tid; i < SAMPLE; i += 256) {
      float4 q = pcb[i];
      float4 t;
      t.x = -2.0f*q.x; t.y = -2.0f*q.y; t.z = -2.0f*q.z;
      t.w = q.x*q.x + q.y*q.y + q.z*q.z;
      sp4[i] = t;
    }
    const float* vb = verts + (size_t)b * NV * 3;
    const int vbase = slice * 128;
    float vx[4], vy[4], vz[4], nv[4], mn[4];
#pragma unroll
    for (int j = 0; j < 4; ++j) {
      int v = vbase + j * 32 + g;
      int vc = (v < NV) ? v : 0;
      vx[j] = vb[vc*3]; vy[j] = vb[vc*3+1]; vz[j] = vb[vc*3+2];
      nv[j] = vx[j]*vx[j] + vy[j]*vy[j] + vz[j]*vz[j];
      mn[j] = INFINITY;
    }
    __syncthreads();
    const int ps = s * 128;
    for (int i = 0; i < 128; ++i) {
      float4 pt = sp4[ps + i];
#pragma unroll
      for (int j = 0; j < 4; ++j) {
        float t = fmaf(vz[j], pt.z, fmaf(vy[j], pt.y, fmaf(vx[j], pt.x, pt.w)));
        mn[j] = fminf(mn[j], t);
      }
    }
#pragma unroll
    for (int j = 0; j < 4; ++j) {
      vmin[s * 128 + j * 32 + g] = mn[j];
      if (s == 0) nvl[j * 32 + g] = nv[j];
    }
    __syncthreads();
    if (tid < 128 && (vbase + tid) < NV) {
      float m = vmin[tid];
#pragma unroll
      for (int ss = 1; ss < 8; ++ss) m = fminf(m, vmin[ss * 128 + tid]);
      val = (m + nvl[tid]) * B_SCALE;
    }
  }

  float r = waveReduceSum(val);
  if ((tid & 63) == 0) red[tid >> 6] = r;
  __syncthreads();
  if (tid == 0) atomicAdd(out, red[0] + red[1] + red[2] + red[3]);
}

extern "C" void kernel_launch(void* const* d_in, const int* in_sizes, int n_in,
                              void* d_out, int out_size, void* d_ws, size_t ws_size,
                              hipStream_t stream) {
  const float* real   = (const float*)d_in[0];
  // d_in[1] = synth (unused), d_in[3] = faces (unused)
  const float* verts  = (const float*)d_in[2];
  const float* center = (const float*)d_in[4];
  const float* M      = (const float*)d_in[5];
  const float* cube   = (const float*)d_in[6];
  float* out = (float*)d_out;

  uint8_t* w = (uint8_t*)d_ws;
  float4*   pcl4    = (float4*)(w + WS_PCL);
  uint32_t* histp   = (uint32_t*)(w + WS_HISTP);
  uint64_t* candg   = (uint64_t*)(w + WS_CAND);
  float*    candrvg = (float*)(w + WS_CANDRV);
  uint32_t* cnts    = (uint32_t*)(w + WS_CNT);
  uint32_t* ccnts   = (uint32_t*)(w + WS_CCNT);

  static int coop = -1;
  if (coop < 0) {
    int dev = 0, v = 0;
    (void)hipGetDevice(&dev);
    if (hipDeviceGetAttribute(&v, hipDeviceAttributeCooperativeLaunch, dev) != hipSuccess) v = 0;
    coop = v ? 1 : 0;
  }

  if (coop == 1 && ws_size >= (size_t)WS_NEEDED) {
    const float4* real4 = (const float4*)real;
    void* args[] = {
      (void*)&real4, (void*)&verts, (void*)&center, (void*)&M, (void*)&cube,
      (void*)&out, (void*)&pcl4, (void*)&histp, (void*)&candg, (void*)&candrvg,
      (void*)&cnts, (void*)&ccnts
    };
    hipError_t e = hipLaunchCooperativeKernel(
        reinterpret_cast<void*>(fused_kernel), dim3(BATCH * 4), dim3(1024),
        args, 0, stream);
    if (e == hipSuccess) return;
    (void)hipGetLastError();  // clear and fall through to fallback
  }

  // Fallback: verified 2-kernel path.
  select_kernel<<<dim3(BATCH), dim3(1024), 0, stream>>>(
      (const float4*)real, center, M, cube, pcl4, out);
  dist_kernel<<<dim3(NA_BLOCKS + NB_BLOCKS), dim3(256), 0, stream>>>(
      verts, pcl4, out);
}

// Round 3
// 109.864 us; speedup vs baseline: 2.2989x; 2.2989x over previous
//
#include <hip/hip_runtime.h>
#include <stdint.h>
#include <math.h>

#define NPIX   16384
#define SAMPLE 1024
#define NV     778
#define BATCH  64

#define A_SCALE (1.0f / (float)(BATCH * SAMPLE))
#define B_SCALE (1.0f / (float)(BATCH * NV))

// ---------------------------------------------------------------------------
// Threefry-2x32, 20 rounds — matches jax._src.prng lowering exactly.
// ---------------------------------------------------------------------------
__device__ __forceinline__ uint32_t rotl32(uint32_t v, int r) {
  return (v << r) | (v >> (32 - r));
}

__device__ __forceinline__ uint32_t threefry_bits(uint32_t g) {
  // key(1) = (0,1); partitionable path: x0 = counts_hi = 0, x1 = g; out h0^h1.
  uint32_t ks0 = 0u, ks1 = 1u;
  uint32_t ks2 = ks0 ^ ks1 ^ 0x1BD11BDAu;
  uint32_t x0 = 0u + ks0, x1 = g + ks1;
#define TF_R(r) { x0 += x1; x1 = rotl32(x1, (r)); x1 ^= x0; }
  TF_R(13) TF_R(15) TF_R(26) TF_R(6)
  x0 += ks1; x1 += ks2 + 1u;
  TF_R(17) TF_R(29) TF_R(16) TF_R(24)
  x0 += ks2; x1 += ks0 + 2u;
  TF_R(13) TF_R(15) TF_R(26) TF_R(6)
  x0 += ks0; x1 += ks1 + 3u;
  TF_R(17) TF_R(29) TF_R(16) TF_R(24)
  x0 += ks1; x1 += ks2 + 4u;
  TF_R(13) TF_R(15) TF_R(26) TF_R(6)
  x0 += ks2; x1 += ks0 + 5u;
#undef TF_R
  return x0 ^ x1;
}

__device__ __forceinline__ float waveReduceSum(float v) {
#pragma unroll
  for (int off = 32; off > 0; off >>= 1) v += __shfl_down(v, off, 64);
  return v;
}

// Deterministic block-wide exclusive scan over 1024 threads (16 waves).
// All threads must call; returns exclusive prefix; *total gets block sum.
// Entry barrier protects swt/soffs reuse across consecutive calls.
__device__ __forceinline__ uint32_t blockExclScan1024(
    uint32_t v, volatile uint32_t* swt, volatile uint32_t* soffs,
    uint32_t* total) {
  const int tid = threadIdx.x;
  const int lane = tid & 63;
  const int wv = tid >> 6;
  __syncthreads();
  uint32_t incl = v;
#pragma unroll
  for (int off = 1; off < 64; off <<= 1) {
    uint32_t u = __shfl_up(incl, off, 64);
    if (lane >= off) incl += u;
  }
  if (lane == 63) swt[wv] = incl;
  __syncthreads();
  if (tid < 16) {
    uint32_t t = swt[tid], s = t;
#pragma unroll
    for (int off = 1; off < 16; off <<= 1) {
      uint32_t u = __shfl_up(s, off, 64);
      if (lane >= off) s += u;
    }
    soffs[tid] = s - t;
  }
  __syncthreads();
  *total = soffs[15] + swt[15];
  return soffs[wv] + incl - v;
}

// ---------------------------------------------------------------------------
// Mega kernel: 256 blocks x 1024 threads; block = (batch b, quarter q).
// Each block REDUNDANTLY computes its batch's full selection (score -> LDS
// hist -> suffix scan -> deterministic scan-based compaction into LDS sp4,
// staged as (-2x,-2y,-2z,|p|^2)).  Determinism (no atomics) guarantees all
// 4 blocks of a batch hold identical sp4.  Then the verified phase-4
// chamfer: A-dir = points q*256..+255 vs all verts; B-dir = verts q*195..
// vs all points.  Block partials atomicAdd into out (pre-zeroed by memset).
// ---------------------------------------------------------------------------
__global__ __launch_bounds__(1024) void mega_kernel(
    const float4* __restrict__ real4,
    const float* __restrict__ verts,
    const float* __restrict__ center,
    const float* __restrict__ M,
    const float* __restrict__ cube,
    float* __restrict__ out) {
  const int bq = blockIdx.x;
  const int b = bq >> 2, q = bq & 3;
  const int tid = threadIdx.x;
  const int lane = tid & 63;
  const int wv = tid >> 6;

  // LDS layout
  __shared__ __align__(16) uint8_t shbuf[53408];
  float4*   sv4    = (float4*)shbuf;               // 778*16  = 12448
  float4*   sp4    = (float4*)(shbuf + 12448);     // 1024*16 = 16384
  float*    fbuf   = (float*)(shbuf + 28832);      // 16*256*4= 16384
  uint32_t* hist   = (uint32_t*)(shbuf + 45216);   // 512*4   = 2048
  uint64_t* cand   = (uint64_t*)(shbuf + 47264);   // 512*8   = 4096
  float*    candrv = (float*)(shbuf + 51360);      // 512*4   = 2048
  __shared__ uint32_t wt[8], offs[8];
  __shared__ uint32_t swt[16], soffs[16];
  __shared__ float sh_minv[6], sh_c[3], sh_hb[3];
  __shared__ uint32_t sh_bstar, sh_above;
  __shared__ float red[16];

  if (tid == 0) {
    const float* m = M + (size_t)b * 9;
    float m00=m[0], m01=m[1], m02=m[2];
    float m10=m[3], m11=m[4], m12=m[5];
    float m20=m[6], m21=m[7], m22=m[8];
    float c00 = m11*m22 - m12*m21;
    float c10 = m12*m20 - m10*m22;
    float c20 = m10*m21 - m11*m20;
    float det = m00*c00 + m01*c10 + m02*c20;
    float id = 1.0f / det;
    sh_minv[0] = c00 * id;
    sh_minv[1] = (m02*m21 - m01*m22) * id;
    sh_minv[2] = (m01*m12 - m02*m11) * id;
    sh_minv[3] = c10 * id;
    sh_minv[4] = (m00*m22 - m02*m20) * id;
    sh_minv[5] = (m02*m10 - m00*m12) * id;
    sh_c[0] = center[b*3+0]; sh_c[1] = center[b*3+1]; sh_c[2] = center[b*3+2];
    sh_hb[0] = cube[b*3+0]*0.5f; sh_hb[1] = cube[b*3+1]*0.5f; sh_hb[2] = cube[b*3+2]*0.5f;
  }
  if (tid < 512) hist[tid] = 0u;

  // Stage verts (used by chamfer; also provides |v|^2 for B-dir sums).
  const float* vb = verts + (size_t)b * NV * 3;
  for (int v = tid; v < NV; v += 1024) {
    float x = vb[v*3], y = vb[v*3+1], z = vb[v*3+2];
    float4 t;
    t.x = -2.0f*x; t.y = -2.0f*y; t.z = -2.0f*z; t.w = x*x + y*y + z*z;
    sv4[v] = t;
  }

  // Score full batch in-register: 16 px/thread, p = e4*4096 + tid*4 + c.
  uint32_t uv[16];
  float    rvv[16];
  const float4* rb4 = real4 + (size_t)b * (NPIX / 4);
#pragma unroll
  for (int e4 = 0; e4 < 4; ++e4) {
    float4 im = rb4[e4 * 1024 + tid];
    uint32_t base = (uint32_t)(b * NPIX + e4 * 4096) + (uint32_t)(tid << 2);
    rvv[e4*4+0] = im.x; rvv[e4*4+1] = im.y; rvv[e4*4+2] = im.z; rvv[e4*4+3] = im.w;
    uv[e4*4+0] = (im.x <= 0.99f) ? ((threefry_bits(base + 0u) >> 9) + 1u) : 0u;
    uv[e4*4+1] = (im.y <= 0.99f) ? ((threefry_bits(base + 1u) >> 9) + 1u) : 0u;
    uv[e4*4+2] = (im.z <= 0.99f) ? ((threefry_bits(base + 2u) >> 9) + 1u) : 0u;
    uv[e4*4+3] = (im.w <= 0.99f) ? ((threefry_bits(base + 3u) >> 9) + 1u) : 0u;
  }
  __syncthreads();   // hist zeroed, sv4 staged

  // Histogram over uniform top-9 bits.
#pragma unroll
  for (int e = 0; e < 16; ++e)
    if (uv[e]) atomicAdd(&hist[(uv[e] - 1u) >> 14], 1u);
  __syncthreads();

  // Suffix scan over 512 buckets -> boundary bucket bstar, count above.
  uint32_t cnt = 0, sfx = 0;
  if (tid < 512) {
    cnt = hist[tid];
    sfx = cnt;
#pragma unroll
    for (int off = 1; off < 64; off <<= 1) {
      uint32_t u = __shfl_down(sfx, off, 64);
      if (lane + off < 64) sfx += u;
    }
    if (lane == 0) wt[wv] = sfx;
  }
  __syncthreads();
  if (tid < 8) {
    uint32_t t = wt[tid], s = t;
#pragma unroll
    for (int off = 1; off < 8; off <<= 1) {
      uint32_t u = __shfl_down(s, off, 64);
      if (tid + off < 8) s += u;
    }
    offs[tid] = s - t;
  }
  __syncthreads();
  if (tid < 512) {
    uint32_t tot = sfx + offs[wv];   // keys in buckets >= tid
    uint32_t above = tot - cnt;      // keys in buckets >  tid
    if (tot >= SAMPLE && above < SAMPLE && cnt > 0) {
      sh_bstar = (uint32_t)tid;
      sh_above = above;
    }
  }
  __syncthreads();
  const int bstar = (int)sh_bstar;
  const uint32_t above = sh_above;
  const uint32_t kneed = SAMPLE - above;

  // Emit helper: transform + stage directly into LDS sp4 as
  // (-2x', -2y', -2z', |p'|^2).
  auto emit = [&](int p, float depth01, uint32_t slot) {
    int i = p >> 7, j = p & 127;
    float tj = (2.0f * (float)j) / 127.0f - 1.0f;
    float ti = (2.0f * (float)i) / 127.0f - 1.0f;
    float u0 = (tj + 1.0f) * 64.0f;
    float u1 = (ti + 1.0f) * 64.0f;
    float d  = depth01 * sh_hb[2] + sh_c[2];
    float w0 = sh_minv[0]*u0 + sh_minv[1]*u1 + sh_minv[2];
    float w1 = sh_minv[3]*u0 + sh_minv[4]*u1 + sh_minv[5];
    float x = (w0 - 320.0f) * d / 588.03f;
    float y = (w1 - 240.0f) * d / 587.07f;
    float ox = (x - sh_c[0]) / sh_hb[0];
    float oy = (y - sh_c[1]) / sh_hb[1];
    float oz = (d - sh_c[2]) / sh_hb[2];
    float4 t;
    t.x = -2.0f*ox; t.y = -2.0f*oy; t.z = -2.0f*oz;
    t.w = ox*ox + oy*oy + oz*oz;
    sp4[slot] = t;
  };

  // Deterministic compaction: per-thread counts -> block scans -> emit.
  uint32_t ch = 0, ce = 0;
#pragma unroll
  for (int e = 0; e < 16; ++e) {
    int bk = uv[e] ? (int)((uv[e] - 1u) >> 14) : -1;
    ch += (bk > bstar) ? 1u : 0u;
    ce += (bk == bstar) ? 1u : 0u;
  }
  uint32_t htot, etot;
  uint32_t hoff = blockExclScan1024(ch, swt, soffs, &htot);
  uint32_t eoff = blockExclScan1024(ce, swt, soffs, &etot);

  {
    uint32_t h = hoff, eo = eoff;
#pragma unroll
    for (int e = 0; e < 16; ++e) {
      uint32_t v = uv[e];
      int bk = v ? (int)((v - 1u) >> 14) : -1;
      int p = (e >> 2) * 4096 + (tid << 2) + (e & 3);
      if (bk > bstar) {
        emit(p, rvv[e], h++);
      } else if (bk == bstar) {
        if (eo < 512u) {
          cand[eo] = ((uint64_t)v << 14) | (uint64_t)(16383 - p);
          candrv[eo] = rvv[e];
        }
        eo++;
      }
    }
  }
  __syncthreads();   // cand + hi-emits complete

  // Boundary-bucket rank-select (parallel: one candidate per thread).
  uint32_t c = etot; if (c > 512u) c = 512u;
  uint32_t selbit = 0; uint64_t ki = 0;
  if (tid < (int)c) {
    ki = cand[tid];
    uint32_t rank = 0;
    for (uint32_t j2 = 0; j2 < c; ++j2) rank += (cand[j2] > ki) ? 1u : 0u;
    selbit = (rank < kneed) ? 1u : 0u;   // keys unique -> exactly kneed
  }
  uint32_t stot;
  uint32_t soff2 = blockExclScan1024(selbit, swt, soffs, &stot);
  if (selbit) {
    int p = 16383 - (int)(ki & 0x3FFFull);
    emit(p, candrv[tid], above + soff2);
  }
  __syncthreads();   // sp4[0..1023] complete and identical across q-blocks

  // ---- Chamfer (verified phase-4 structure) ----
  float val = 0.0f;
  const int sub = tid & 63;
  const int seg16 = tid >> 6;

  // dir A: points q*256..q*256+255 vs ALL verts; 16-way vert split.
  {
    float px[4], py[4], pz[4], mnA[4];
#pragma unroll
    for (int j = 0; j < 4; ++j) {
      float4 sp = sp4[q * 256 + j * 64 + sub];
      px[j] = -0.5f * sp.x; py[j] = -0.5f * sp.y; pz[j] = -0.5f * sp.z;
      mnA[j] = INFINITY;
    }
    int vs = seg16 * 49, ve = vs + 49; if (ve > NV) ve = NV;
    for (int v = vs; v < ve; ++v) {
      float4 vv = sv4[v];                       // wave-uniform broadcast
#pragma unroll
      for (int j = 0; j < 4; ++j) {
        float t = fmaf(pz[j], vv.z, fmaf(py[j], vv.y, fmaf(px[j], vv.x, vv.w)));
        mnA[j] = fminf(mnA[j], t);
      }
    }
#pragma unroll
    for (int j = 0; j < 4; ++j) fbuf[seg16 * 256 + j * 64 + sub] = mnA[j];
  }
  __syncthreads();
  if (tid < 256) {
    float m = fbuf[tid];
#pragma unroll
    for (int s2 = 1; s2 < 16; ++s2) m = fminf(m, fbuf[s2 * 256 + tid]);
    val += (m + sp4[q * 256 + tid].w) * A_SCALE;
  }
  __syncthreads();

  // dir B: verts q*195.. vs ALL points; 16-way point split.
  {
    const int vbase = q * 195;
    int nsl = NV - vbase; if (nsl > 195) nsl = 195;
    float vx[4], vy[4], vz[4], mnB[4];
#pragma unroll
    for (int j = 0; j < 4; ++j) {
      int vloc = j * 64 + sub;
      int vi = (vloc < nsl) ? (vbase + vloc) : 0;
      float4 sv = sv4[vi];
      vx[j] = -0.5f * sv.x; vy[j] = -0.5f * sv.y; vz[j] = -0.5f * sv.z;
      mnB[j] = INFINITY;
    }
    int is = seg16 * 64;
    for (int i = 0; i < 64; ++i) {
      float4 pp = sp4[is + i];                  // wave-uniform broadcast
#pragma unroll
      for (int j = 0; j < 4; ++j) {
        float t = fmaf(vz[j], pp.z, fmaf(vy[j], pp.y, fmaf(vx[j], pp.x, pp.w)));
        mnB[j] = fminf(mnB[j], t);
      }
    }
#pragma unroll
    for (int j = 0; j < 4; ++j) fbuf[seg16 * 256 + j * 64 + sub] = mnB[j];
  }
  __syncthreads();
  {
    const int vbase = q * 195;
    int nsl = NV - vbase; if (nsl > 195) nsl = 195;
    if (tid < nsl) {
      float m = fbuf[tid];
#pragma unroll
      for (int s2 = 1; s2 < 16; ++s2) m = fminf(m, fbuf[s2 * 256 + tid]);
      val += (m + sv4[vbase + tid].w) * B_SCALE;
    }
  }

  float r = waveReduceSum(val);
  if (lane == 0) red[wv] = r;
  __syncthreads();
  if (tid == 0) {
    float s = 0.0f;
#pragma unroll
    for (int i = 0; i < 16; ++i) s += red[i];
    atomicAdd(out, s);
  }
}

extern "C" void kernel_launch(void* const* d_in, const int* in_sizes, int n_in,
                              void* d_out, int out_size, void* d_ws, size_t ws_size,
                              hipStream_t stream) {
  const float* real   = (const float*)d_in[0];
  // d_in[1] = synth (unused), d_in[3] = faces (unused)
  const float* verts  = (const float*)d_in[2];
  const float* center = (const float*)d_in[4];
  const float* M      = (const float*)d_in[5];
  const float* cube   = (const float*)d_in[6];
  float* out = (float*)d_out;

  hipMemsetAsync(out, 0, sizeof(float), stream);
  mega_kernel<<<dim3(BATCH * 4), dim3(1024), 0, stream>>>(
      (const float4*)real, verts, center, M, cube, out);
}

// Round 4
// 108.285 us; speedup vs baseline: 2.3324x; 1.0146x over previous
//
#include <hip/hip_runtime.h>
#include <stdint.h>
#include <math.h>

#define NPIX   16384
#define SAMPLE 1024
#define NV     778
#define BATCH  64

#define A_SCALE (1.0f / (float)(BATCH * SAMPLE))
#define B_SCALE (1.0f / (float)(BATCH * NV))

// Workspace layout (bytes)
#define WS_UBITS  0u          // 64*16384*4 = 4194304
#define WS_HISTG  4194304u    // 256*512*4  = 524288
#define WS_NEEDED 4718592u

// ---------------------------------------------------------------------------
// Threefry-2x32, 20 rounds — matches jax._src.prng lowering exactly.
// ---------------------------------------------------------------------------
__device__ __forceinline__ uint32_t rotl32(uint32_t v, int r) {
  return (v << r) | (v >> (32 - r));
}

__device__ __forceinline__ uint32_t threefry_bits(uint32_t g) {
  // key(1) = (0,1); partitionable path: x0 = counts_hi = 0, x1 = g; out h0^h1.
  uint32_t ks0 = 0u, ks1 = 1u;
  uint32_t ks2 = ks0 ^ ks1 ^ 0x1BD11BDAu;
  uint32_t x0 = 0u + ks0, x1 = g + ks1;
#define TF_R(r) { x0 += x1; x1 = rotl32(x1, (r)); x1 ^= x0; }
  TF_R(13) TF_R(15) TF_R(26) TF_R(6)
  x0 += ks1; x1 += ks2 + 1u;
  TF_R(17) TF_R(29) TF_R(16) TF_R(24)
  x0 += ks2; x1 += ks0 + 2u;
  TF_R(13) TF_R(15) TF_R(26) TF_R(6)
  x0 += ks0; x1 += ks1 + 3u;
  TF_R(17) TF_R(29) TF_R(16) TF_R(24)
  x0 += ks1; x1 += ks2 + 4u;
  TF_R(13) TF_R(15) TF_R(26) TF_R(6)
  x0 += ks2; x1 += ks0 + 5u;
#undef TF_R
  return x0 ^ x1;
}

__device__ __forceinline__ float waveReduceSum(float v) {
#pragma unroll
  for (int off = 32; off > 0; off >>= 1) v += __shfl_down(v, off, 64);
  return v;
}

// Deterministic block-wide exclusive scan over 1024 threads (16 waves).
// All threads must call; returns exclusive prefix; *total gets block sum.
// Entry barrier protects swt/soffs reuse across consecutive calls.
__device__ __forceinline__ uint32_t blockExclScan1024(
    uint32_t v, volatile uint32_t* swt, volatile uint32_t* soffs,
    uint32_t* total) {
  const int tid = threadIdx.x;
  const int lane = tid & 63;
  const int wv = tid >> 6;
  __syncthreads();
  uint32_t incl = v;
#pragma unroll
  for (int off = 1; off < 64; off <<= 1) {
    uint32_t u = __shfl_up(incl, off, 64);
    if (lane >= off) incl += u;
  }
  if (lane == 63) swt[wv] = incl;
  __syncthreads();
  if (tid < 16) {
    uint32_t t = swt[tid], s = t;
#pragma unroll
    for (int off = 1; off < 16; off <<= 1) {
      uint32_t u = __shfl_up(s, off, 64);
      if (lane >= off) s += u;
    }
    soffs[tid] = s - t;
  }
  __syncthreads();
  *total = soffs[15] + swt[15];
  return soffs[wv] + incl - v;
}

// ---------------------------------------------------------------------------
// K1: score. 256 blocks x 1024 thr; block = (batch b, quarter q). Each block
// hashes ONLY its quarter (4 px/thread), stores 23-bit u-keys (+1; 0=masked)
// to global ubits, and its per-quarter 512-bucket histogram (plain stores —
// no cross-block zero/atomic needed on poisoned workspace). Also zeroes out.
// ---------------------------------------------------------------------------
__global__ __launch_bounds__(1024) void score_kernel(
    const float4* __restrict__ real4,
    uint32_t* __restrict__ ubits,
    uint32_t* __restrict__ histg,
    float* __restrict__ out) {
  const int bq = blockIdx.x;
  const int b = bq >> 2, q = bq & 3;
  const int tid = threadIdx.x;
  __shared__ uint32_t hist[512];

  if (bq == 0 && tid == 0) out[0] = 0.0f;
  if (tid < 512) hist[tid] = 0u;

  float4 im = real4[(size_t)b * 4096 + q * 1024 + tid];
  uint32_t base = (uint32_t)(b * NPIX + q * 4096) + (uint32_t)(tid << 2);
  uint32_t u0 = (im.x <= 0.99f) ? ((threefry_bits(base + 0u) >> 9) + 1u) : 0u;
  uint32_t u1 = (im.y <= 0.99f) ? ((threefry_bits(base + 1u) >> 9) + 1u) : 0u;
  uint32_t u2 = (im.z <= 0.99f) ? ((threefry_bits(base + 2u) >> 9) + 1u) : 0u;
  uint32_t u3 = (im.w <= 0.99f) ? ((threefry_bits(base + 3u) >> 9) + 1u) : 0u;

  uint4 st; st.x = u0; st.y = u1; st.z = u2; st.w = u3;
  ((uint4*)ubits)[(size_t)b * 4096 + q * 1024 + tid] = st;

  __syncthreads();   // hist zeroed
  if (u0) atomicAdd(&hist[(u0 - 1u) >> 14], 1u);
  if (u1) atomicAdd(&hist[(u1 - 1u) >> 14], 1u);
  if (u2) atomicAdd(&hist[(u2 - 1u) >> 14], 1u);
  if (u3) atomicAdd(&hist[(u3 - 1u) >> 14], 1u);
  __syncthreads();   // atomics done
  if (tid < 512) histg[(size_t)bq * 512 + tid] = hist[tid];
}

// ---------------------------------------------------------------------------
// K2: select + chamfer. 256 blocks x 1024 thr; block = (batch b, quarter q).
// Reads the batch's ubits (L2) + per-quarter hists, redundantly computes the
// batch's selection with the verified deterministic scan-compaction into LDS
// sp4, then runs the verified chamfer on its quarter slice.
// ---------------------------------------------------------------------------
__global__ __launch_bounds__(1024) void chamsel_kernel(
    const float4* __restrict__ real4,
    const float* __restrict__ verts,
    const float* __restrict__ center,
    const float* __restrict__ M,
    const float* __restrict__ cube,
    const uint32_t* __restrict__ ubits,
    const uint32_t* __restrict__ histg,
    float* __restrict__ out) {
  const int bq = blockIdx.x;
  const int b = bq >> 2, q = bq & 3;
  const int tid = threadIdx.x;
  const int lane = tid & 63;
  const int wv = tid >> 6;

  // LDS layout
  __shared__ __align__(16) uint8_t shbuf[51360];
  float4*   sv4    = (float4*)shbuf;               // 778*16  = 12448
  float4*   sp4    = (float4*)(shbuf + 12448);     // 1024*16 = 16384
  float*    fbuf   = (float*)(shbuf + 28832);      // 16*256*4= 16384
  uint64_t* cand   = (uint64_t*)(shbuf + 45216);   // 512*8   = 4096
  float*    candrv = (float*)(shbuf + 49312);      // 512*4   = 2048
  __shared__ uint32_t wt[8], offs[8];
  __shared__ uint32_t swt[16], soffs[16];
  __shared__ float sh_minv[6], sh_c[3], sh_hb[3];
  __shared__ uint32_t sh_bstar, sh_above;
  __shared__ float red[16];

  if (tid == 0) {
    const float* m = M + (size_t)b * 9;
    float m00=m[0], m01=m[1], m02=m[2];
    float m10=m[3], m11=m[4], m12=m[5];
    float m20=m[6], m21=m[7], m22=m[8];
    float c00 = m11*m22 - m12*m21;
    float c10 = m12*m20 - m10*m22;
    float c20 = m10*m21 - m11*m20;
    float det = m00*c00 + m01*c10 + m02*c20;
    float id = 1.0f / det;
    sh_minv[0] = c00 * id;
    sh_minv[1] = (m02*m21 - m01*m22) * id;
    sh_minv[2] = (m01*m12 - m02*m11) * id;
    sh_minv[3] = c10 * id;
    sh_minv[4] = (m00*m22 - m02*m20) * id;
    sh_minv[5] = (m02*m10 - m00*m12) * id;
    sh_c[0] = center[b*3+0]; sh_c[1] = center[b*3+1]; sh_c[2] = center[b*3+2];
    sh_hb[0] = cube[b*3+0]*0.5f; sh_hb[1] = cube[b*3+1]*0.5f; sh_hb[2] = cube[b*3+2]*0.5f;
  }

  // Stage verts (used by chamfer; also provides |v|^2 for B-dir sums).
  const float* vb = verts + (size_t)b * NV * 3;
  for (int v = tid; v < NV; v += 1024) {
    float x = vb[v*3], y = vb[v*3+1], z = vb[v*3+2];
    float4 t;
    t.x = -2.0f*x; t.y = -2.0f*y; t.z = -2.0f*z; t.w = x*x + y*y + z*z;
    sv4[v] = t;
  }

  // Load full-batch u-keys + depths: 16 px/thread, p = e4*4096 + tid*4 + c.
  uint32_t uv[16];
  float    rvv[16];
  const float4* rb4 = real4 + (size_t)b * (NPIX / 4);
  const uint4*  ub4 = (const uint4*)ubits + (size_t)b * (NPIX / 4);
#pragma unroll
  for (int e4 = 0; e4 < 4; ++e4) {
    float4 im = rb4[e4 * 1024 + tid];
    uint4  uu = ub4[e4 * 1024 + tid];
    rvv[e4*4+0] = im.x; rvv[e4*4+1] = im.y; rvv[e4*4+2] = im.z; rvv[e4*4+3] = im.w;
    uv[e4*4+0] = uu.x; uv[e4*4+1] = uu.y; uv[e4*4+2] = uu.z; uv[e4*4+3] = uu.w;
  }

  // Suffix scan over summed 512-bucket hist -> bstar, count above.
  uint32_t cnt = 0, sfx = 0;
  if (tid < 512) {
    const uint32_t* hp = histg + (size_t)(b << 2) * 512 + tid;
    cnt = hp[0] + hp[512] + hp[1024] + hp[1536];
    sfx = cnt;
#pragma unroll
    for (int off = 1; off < 64; off <<= 1) {
      uint32_t u = __shfl_down(sfx, off, 64);
      if (lane + off < 64) sfx += u;
    }
    if (lane == 0) wt[wv] = sfx;
  }
  __syncthreads();
  if (tid < 8) {
    uint32_t t = wt[tid], s = t;
#pragma unroll
    for (int off = 1; off < 8; off <<= 1) {
      uint32_t u = __shfl_down(s, off, 64);
      if (tid + off < 8) s += u;
    }
    offs[tid] = s - t;
  }
  __syncthreads();
  if (tid < 512) {
    uint32_t tot = sfx + offs[wv];   // keys in buckets >= tid
    uint32_t above = tot - cnt;      // keys in buckets >  tid
    if (tot >= SAMPLE && above < SAMPLE && cnt > 0) {
      sh_bstar = (uint32_t)tid;
      sh_above = above;
    }
  }
  __syncthreads();
  const int bstar = (int)sh_bstar;
  const uint32_t above = sh_above;
  const uint32_t kneed = SAMPLE - above;

  // Emit helper: transform + stage directly into LDS sp4 as
  // (-2x', -2y', -2z', |p'|^2).
  auto emit = [&](int p, float depth01, uint32_t slot) {
    int i = p >> 7, j = p & 127;
    float tj = (2.0f * (float)j) / 127.0f - 1.0f;
    float ti = (2.0f * (float)i) / 127.0f - 1.0f;
    float u0 = (tj + 1.0f) * 64.0f;
    float u1 = (ti + 1.0f) * 64.0f;
    float d  = depth01 * sh_hb[2] + sh_c[2];
    float w0 = sh_minv[0]*u0 + sh_minv[1]*u1 + sh_minv[2];
    float w1 = sh_minv[3]*u0 + sh_minv[4]*u1 + sh_minv[5];
    float x = (w0 - 320.0f) * d / 588.03f;
    float y = (w1 - 240.0f) * d / 587.07f;
    float ox = (x - sh_c[0]) / sh_hb[0];
    float oy = (y - sh_c[1]) / sh_hb[1];
    float oz = (d - sh_c[2]) / sh_hb[2];
    float4 t;
    t.x = -2.0f*ox; t.y = -2.0f*oy; t.z = -2.0f*oz;
    t.w = ox*ox + oy*oy + oz*oz;
    sp4[slot] = t;
  };

  // Deterministic compaction: per-thread counts -> block scans -> emit.
  uint32_t ch = 0, ce = 0;
#pragma unroll
  for (int e = 0; e < 16; ++e) {
    int bk = uv[e] ? (int)((uv[e] - 1u) >> 14) : -1;
    ch += (bk > bstar) ? 1u : 0u;
    ce += (bk == bstar) ? 1u : 0u;
  }
  uint32_t htot, etot;
  uint32_t hoff = blockExclScan1024(ch, swt, soffs, &htot);
  uint32_t eoff = blockExclScan1024(ce, swt, soffs, &etot);

  {
    uint32_t h = hoff, eo = eoff;
#pragma unroll
    for (int e = 0; e < 16; ++e) {
      uint32_t v = uv[e];
      int bk = v ? (int)((v - 1u) >> 14) : -1;
      int p = (e >> 2) * 4096 + (tid << 2) + (e & 3);
      if (bk > bstar) {
        emit(p, rvv[e], h++);
      } else if (bk == bstar) {
        if (eo < 512u) {
          cand[eo] = ((uint64_t)v << 14) | (uint64_t)(16383 - p);
          candrv[eo] = rvv[e];
        }
        eo++;
      }
    }
  }
  __syncthreads();   // cand + hi-emits complete

  // Boundary-bucket rank-select (parallel: one candidate per thread).
  uint32_t c = etot; if (c > 512u) c = 512u;
  uint32_t selbit = 0; uint64_t ki = 0;
  if (tid < (int)c) {
    ki = cand[tid];
    uint32_t rank = 0;
    for (uint32_t j2 = 0; j2 < c; ++j2) rank += (cand[j2] > ki) ? 1u : 0u;
    selbit = (rank < kneed) ? 1u : 0u;   // keys unique -> exactly kneed
  }
  uint32_t stot;
  uint32_t soff2 = blockExclScan1024(selbit, swt, soffs, &stot);
  if (selbit) {
    int p = 16383 - (int)(ki & 0x3FFFull);
    emit(p, candrv[tid], above + soff2);
  }
  __syncthreads();   // sp4[0..1023] complete and identical across q-blocks

  // ---- Chamfer (verified structure) ----
  float val = 0.0f;
  const int sub = tid & 63;
  const int seg16 = tid >> 6;

  // dir A: points q*256..q*256+255 vs ALL verts; 16-way vert split.
  {
    float px[4], py[4], pz[4], mnA[4];
#pragma unroll
    for (int j = 0; j < 4; ++j) {
      float4 sp = sp4[q * 256 + j * 64 + sub];
      px[j] = -0.5f * sp.x; py[j] = -0.5f * sp.y; pz[j] = -0.5f * sp.z;
      mnA[j] = INFINITY;
    }
    int vs = seg16 * 49, ve = vs + 49; if (ve > NV) ve = NV;
    for (int v = vs; v < ve; ++v) {
      float4 vv = sv4[v];                       // wave-uniform broadcast
#pragma unroll
      for (int j = 0; j < 4; ++j) {
        float t = fmaf(pz[j], vv.z, fmaf(py[j], vv.y, fmaf(px[j], vv.x, vv.w)));
        mnA[j] = fminf(mnA[j], t);
      }
    }
#pragma unroll
    for (int j = 0; j < 4; ++j) fbuf[seg16 * 256 + j * 64 + sub] = mnA[j];
  }
  __syncthreads();
  if (tid < 256) {
    float m = fbuf[tid];
#pragma unroll
    for (int s2 = 1; s2 < 16; ++s2) m = fminf(m, fbuf[s2 * 256 + tid]);
    val += (m + sp4[q * 256 + tid].w) * A_SCALE;
  }
  __syncthreads();

  // dir B: verts q*195.. vs ALL points; 16-way point split.
  {
    const int vbase = q * 195;
    int nsl = NV - vbase; if (nsl > 195) nsl = 195;
    float vx[4], vy[4], vz[4], mnB[4];
#pragma unroll
    for (int j = 0; j < 4; ++j) {
      int vloc = j * 64 + sub;
      int vi = (vloc < nsl) ? (vbase + vloc) : 0;
      float4 sv = sv4[vi];
      vx[j] = -0.5f * sv.x; vy[j] = -0.5f * sv.y; vz[j] = -0.5f * sv.z;
      mnB[j] = INFINITY;
    }
    int is = seg16 * 64;
    for (int i = 0; i < 64; ++i) {
      float4 pp = sp4[is + i];                  // wave-uniform broadcast
#pragma unroll
      for (int j = 0; j < 4; ++j) {
        float t = fmaf(vz[j], pp.z, fmaf(vy[j], pp.y, fmaf(vx[j], pp.x, pp.w)));
        mnB[j] = fminf(mnB[j], t);
      }
    }
#pragma unroll
    for (int j = 0; j < 4; ++j) fbuf[seg16 * 256 + j * 64 + sub] = mnB[j];
  }
  __syncthreads();
  {
    const int vbase = q * 195;
    int nsl = NV - vbase; if (nsl > 195) nsl = 195;
    if (tid < nsl) {
      float m = fbuf[tid];
#pragma unroll
      for (int s2 = 1; s2 < 16; ++s2) m = fminf(m, fbuf[s2 * 256 + tid]);
      val += (m + sv4[vbase + tid].w) * B_SCALE;
    }
  }

  float r = waveReduceSum(val);
  if (lane == 0) red[wv] = r;
  __syncthreads();
  if (tid == 0) {
    float s = 0.0f;
#pragma unroll
    for (int i = 0; i < 16; ++i) s += red[i];
    atomicAdd(out, s);
  }
}

// ===========================================================================
// Fallback: verified round-3 mega kernel (self-contained select, no ws).
// ===========================================================================
__global__ __launch_bounds__(1024) void mega_kernel(
    const float4* __restrict__ real4,
    const float* __restrict__ verts,
    const float* __restrict__ center,
    const float* __restrict__ M,
    const float* __restrict__ cube,
    float* __restrict__ out) {
  const int bq = blockIdx.x;
  const int b = bq >> 2, q = bq & 3;
  const int tid = threadIdx.x;
  const int lane = tid & 63;
  const int wv = tid >> 6;

  __shared__ __align__(16) uint8_t shbuf[53408];
  float4*   sv4    = (float4*)shbuf;
  float4*   sp4    = (float4*)(shbuf + 12448);
  float*    fbuf   = (float*)(shbuf + 28832);
  uint32_t* hist   = (uint32_t*)(shbuf + 45216);
  uint64_t* cand   = (uint64_t*)(shbuf + 47264);
  float*    candrv = (float*)(shbuf + 51360);
  __shared__ uint32_t wt[8], offs[8];
  __shared__ uint32_t swt[16], soffs[16];
  __shared__ float sh_minv[6], sh_c[3], sh_hb[3];
  __shared__ uint32_t sh_bstar, sh_above;
  __shared__ float red[16];

  if (tid == 0) {
    const float* m = M + (size_t)b * 9;
    float m00=m[0], m01=m[1], m02=m[2];
    float m10=m[3], m11=m[4], m12=m[5];
    float m20=m[6], m21=m[7], m22=m[8];
    float c00 = m11*m22 - m12*m21;
    float c10 = m12*m20 - m10*m22;
    float c20 = m10*m21 - m11*m20;
    float det = m00*c00 + m01*c10 + m02*c20;
    float id = 1.0f / det;
    sh_minv[0] = c00 * id;
    sh_minv[1] = (m02*m21 - m01*m22) * id;
    sh_minv[2] = (m01*m12 - m02*m11) * id;
    sh_minv[3] = c10 * id;
    sh_minv[4] = (m00*m22 - m02*m20) * id;
    sh_minv[5] = (m02*m10 - m00*m12) * id;
    sh_c[0] = center[b*3+0]; sh_c[1] = center[b*3+1]; sh_c[2] = center[b*3+2];
    sh_hb[0] = cube[b*3+0]*0.5f; sh_hb[1] = cube[b*3+1]*0.5f; sh_hb[2] = cube[b*3+2]*0.5f;
  }
  if (tid < 512) hist[tid] = 0u;

  const float* vb = verts + (size_t)b * NV * 3;
  for (int v = tid; v < NV; v += 1024) {
    float x = vb[v*3], y = vb[v*3+1], z = vb[v*3+2];
    float4 t;
    t.x = -2.0f*x; t.y = -2.0f*y; t.z = -2.0f*z; t.w = x*x + y*y + z*z;
    sv4[v] = t;
  }

  uint32_t uv[16];
  float    rvv[16];
  const float4* rb4 = real4 + (size_t)b * (NPIX / 4);
#pragma unroll
  for (int e4 = 0; e4 < 4; ++e4) {
    float4 im = rb4[e4 * 1024 + tid];
    uint32_t base = (uint32_t)(b * NPIX + e4 * 4096) + (uint32_t)(tid << 2);
    rvv[e4*4+0] = im.x; rvv[e4*4+1] = im.y; rvv[e4*4+2] = im.z; rvv[e4*4+3] = im.w;
    uv[e4*4+0] = (im.x <= 0.99f) ? ((threefry_bits(base + 0u) >> 9) + 1u) : 0u;
    uv[e4*4+1] = (im.y <= 0.99f) ? ((threefry_bits(base + 1u) >> 9) + 1u) : 0u;
    uv[e4*4+2] = (im.z <= 0.99f) ? ((threefry_bits(base + 2u) >> 9) + 1u) : 0u;
    uv[e4*4+3] = (im.w <= 0.99f) ? ((threefry_bits(base + 3u) >> 9) + 1u) : 0u;
  }
  __syncthreads();

#pragma unroll
  for (int e = 0; e < 16; ++e)
    if (uv[e]) atomicAdd(&hist[(uv[e] - 1u) >> 14], 1u);
  __syncthreads();

  uint32_t cnt = 0, sfx = 0;
  if (tid < 512) {
    cnt = hist[tid];
    sfx = cnt;
#pragma unroll
    for (int off = 1; off < 64; off <<= 1) {
      uint32_t u = __shfl_down(sfx, off, 64);
      if (lane + off < 64) sfx += u;
    }
    if (lane == 0) wt[wv] = sfx;
  }
  __syncthreads();
  if (tid < 8) {
    uint32_t t = wt[tid], s = t;
#pragma unroll
    for (int off = 1; off < 8; off <<= 1) {
      uint32_t u = __shfl_down(s, off, 64);
      if (tid + off < 8) s += u;
    }
    offs[tid] = s - t;
  }
  __syncthreads();
  if (tid < 512) {
    uint32_t tot = sfx + offs[wv];
    uint32_t above = tot - cnt;
    if (tot >= SAMPLE && above < SAMPLE && cnt > 0) {
      sh_bstar = (uint32_t)tid;
      sh_above = above;
    }
  }
  __syncthreads();
  const int bstar = (int)sh_bstar;
  const uint32_t above = sh_above;
  const uint32_t kneed = SAMPLE - above;

  auto emit = [&](int p, float depth01, uint32_t slot) {
    int i = p >> 7, j = p & 127;
    float tj = (2.0f * (float)j) / 127.0f - 1.0f;
    float ti = (2.0f * (float)i) / 127.0f - 1.0f;
    float u0 = (tj + 1.0f) * 64.0f;
    float u1 = (ti + 1.0f) * 64.0f;
    float d  = depth01 * sh_hb[2] + sh_c[2];
    float w0 = sh_minv[0]*u0 + sh_minv[1]*u1 + sh_minv[2];
    float w1 = sh_minv[3]*u0 + sh_minv[4]*u1 + sh_minv[5];
    float x = (w0 - 320.0f) * d / 588.03f;
    float y = (w1 - 240.0f) * d / 587.07f;
    float ox = (x - sh_c[0]) / sh_hb[0];
    float oy = (y - sh_c[1]) / sh_hb[1];
    float oz = (d - sh_c[2]) / sh_hb[2];
    float4 t;
    t.x = -2.0f*ox; t.y = -2.0f*oy; t.z = -2.0f*oz;
    t.w = ox*ox + oy*oy + oz*oz;
    sp4[slot] = t;
  };

  uint32_t ch = 0, ce = 0;
#pragma unroll
  for (int e = 0; e < 16; ++e) {
    int bk = uv[e] ? (int)((uv[e] - 1u) >> 14) : -1;
    ch += (bk > bstar) ? 1u : 0u;
    ce += (bk == bstar) ? 1u : 0u;
  }
  uint32_t htot, etot;
  uint32_t hoff = blockExclScan1024(ch, swt, soffs, &htot);
  uint32_t eoff = blockExclScan1024(ce, swt, soffs, &etot);

  {
    uint32_t h = hoff, eo = eoff;
#pragma unroll
    for (int e = 0; e < 16; ++e) {
      uint32_t v = uv[e];
      int bk = v ? (int)((v - 1u) >> 14) : -1;
      int p = (e >> 2) * 4096 + (tid << 2) + (e & 3);
      if (bk > bstar) {
        emit(p, rvv[e], h++);
      } else if (bk == bstar) {
        if (eo < 512u) {
          cand[eo] = ((uint64_t)v << 14) | (uint64_t)(16383 - p);
          candrv[eo] = rvv[e];
        }
        eo++;
      }
    }
  }
  __syncthreads();

  uint32_t c = etot; if (c > 512u) c = 512u;
  uint32_t selbit = 0; uint64_t ki = 0;
  if (tid < (int)c) {
    ki = cand[tid];
    uint32_t rank = 0;
    for (uint32_t j2 = 0; j2 < c; ++j2) rank += (cand[j2] > ki) ? 1u : 0u;
    selbit = (rank < kneed) ? 1u : 0u;
  }
  uint32_t stot;
  uint32_t soff2 = blockExclScan1024(selbit, swt, soffs, &stot);
  if (selbit) {
    int p = 16383 - (int)(ki & 0x3FFFull);
    emit(p, candrv[tid], above + soff2);
  }
  __syncthreads();

  float val = 0.0f;
  const int sub = tid & 63;
  const int seg16 = tid >> 6;

  {
    float px[4], py[4], pz[4], mnA[4];
#pragma unroll
    for (int j = 0; j < 4; ++j) {
      float4 sp = sp4[q * 256 + j * 64 + sub];
      px[j] = -0.5f * sp.x; py[j] = -0.5f * sp.y; pz[j] = -0.5f * sp.z;
      mnA[j] = INFINITY;
    }
    int vs = seg16 * 49, ve = vs + 49; if (ve > NV) ve = NV;
    for (int v = vs; v < ve; ++v) {
      float4 vv = sv4[v];
#pragma unroll
      for (int j = 0; j < 4; ++j) {
        float t = fmaf(pz[j], vv.z, fmaf(py[j], vv.y, fmaf(px[j], vv.x, vv.w)));
        mnA[j] = fminf(mnA[j], t);
      }
    }
#pragma unroll
    for (int j = 0; j < 4; ++j) fbuf[seg16 * 256 + j * 64 + sub] = mnA[j];
  }
  __syncthreads();
  if (tid < 256) {
    float m = fbuf[tid];
#pragma unroll
    for (int s2 = 1; s2 < 16; ++s2) m = fminf(m, fbuf[s2 * 256 + tid]);
    val += (m + sp4[q * 256 + tid].w) * A_SCALE;
  }
  __syncthreads();

  {
    const int vbase = q * 195;
    int nsl = NV - vbase; if (nsl > 195) nsl = 195;
    float vx[4], vy[4], vz[4], mnB[4];
#pragma unroll
    for (int j = 0; j < 4; ++j) {
      int vloc = j * 64 + sub;
      int vi = (vloc < nsl) ? (vbase + vloc) : 0;
      float4 sv = sv4[vi];
      vx[j] = -0.5f * sv.x; vy[j] = -0.5f * sv.y; vz[j] = -0.5f * sv.z;
      mnB[j] = INFINITY;
    }
    int is = seg16 * 64;
    for (int i = 0; i < 64; ++i) {
      float4 pp = sp4[is + i];
#pragma unroll
      for (int j = 0; j < 4; ++j) {
        float t = fmaf(vz[j], pp.z, fmaf(vy[j], pp.y, fmaf(vx[j], pp.x, pp.w)));
        mnB[j] = fminf(mnB[j], t);
      }
    }
#pragma unroll
    for (int j = 0; j < 4; ++j) fbuf[seg16 * 256 + j * 64 + sub] = mnB[j];
  }
  __syncthreads();
  {
    const int vbase = q * 195;
    int nsl = NV - vbase; if (nsl > 195) nsl = 195;
    if (tid < nsl) {
      float m = fbuf[tid];
#pragma unroll
      for (int s2 = 1; s2 < 16; ++s2) m = fminf(m, fbuf[s2 * 256 + tid]);
      val += (m + sv4[vbase + tid].w) * B_SCALE;
    }
  }

  float r = waveReduceSum(val);
  if (lane == 0) red[wv] = r;
  __syncthreads();
  if (tid == 0) {
    float s = 0.0f;
#pragma unroll
    for (int i = 0; i < 16; ++i) s += red[i];
    atomicAdd(out, s);
  }
}

extern "C" void kernel_launch(void* const* d_in, const int* in_sizes, int n_in,
                              void* d_out, int out_size, void* d_ws, size_t ws_size,
                              hipStream_t stream) {
  const float* real   = (const float*)d_in[0];
  // d_in[1] = synth (unused), d_in[3] = faces (unused)
  const float* verts  = (const float*)d_in[2];
  const float* center = (const float*)d_in[4];
  const float* M      = (const float*)d_in[5];
  const float* cube   = (const float*)d_in[6];
  float* out = (float*)d_out;

  if (ws_size >= (size_t)WS_NEEDED) {
    uint8_t* w = (uint8_t*)d_ws;
    uint32_t* ubits = (uint32_t*)(w + WS_UBITS);
    uint32_t* histg = (uint32_t*)(w + WS_HISTG);
    score_kernel<<<dim3(BATCH * 4), dim3(1024), 0, stream>>>(
        (const float4*)real, ubits, histg, out);
    chamsel_kernel<<<dim3(BATCH * 4), dim3(1024), 0, stream>>>(
        (const float4*)real, verts, center, M, cube, ubits, histg, out);
  } else {
    hipMemsetAsync(out, 0, sizeof(float), stream);
    mega_kernel<<<dim3(BATCH * 4), dim3(1024), 0, stream>>>(
        (const float4*)real, verts, center, M, cube, out);
  }
}

// Round 5
// 97.560 us; speedup vs baseline: 2.5888x; 1.1099x over previous
//
#include <hip/hip_runtime.h>
#include <stdint.h>
#include <math.h>

#define NPIX   16384
#define SAMPLE 1024
#define NV     778
#define BATCH  64

#define A_SCALE (1.0f / (float)(BATCH * SAMPLE))
#define B_SCALE (1.0f / (float)(BATCH * NV))

// Workspace layout (bytes)
#define WS_UBITS  0u          // 64*16384*4 = 4194304
#define WS_HISTG  4194304u    // 256*512*4  = 524288
#define WS_NEEDED 4718592u

// ---------------------------------------------------------------------------
// Threefry-2x32, 20 rounds — matches jax._src.prng lowering exactly.
// ---------------------------------------------------------------------------
__device__ __forceinline__ uint32_t rotl32(uint32_t v, int r) {
  return (v << r) | (v >> (32 - r));
}

__device__ __forceinline__ uint32_t threefry_bits(uint32_t g) {
  // key(1) = (0,1); partitionable path: x0 = counts_hi = 0, x1 = g; out h0^h1.
  uint32_t ks0 = 0u, ks1 = 1u;
  uint32_t ks2 = ks0 ^ ks1 ^ 0x1BD11BDAu;
  uint32_t x0 = 0u + ks0, x1 = g + ks1;
#define TF_R(r) { x0 += x1; x1 = rotl32(x1, (r)); x1 ^= x0; }
  TF_R(13) TF_R(15) TF_R(26) TF_R(6)
  x0 += ks1; x1 += ks2 + 1u;
  TF_R(17) TF_R(29) TF_R(16) TF_R(24)
  x0 += ks2; x1 += ks0 + 2u;
  TF_R(13) TF_R(15) TF_R(26) TF_R(6)
  x0 += ks0; x1 += ks1 + 3u;
  TF_R(17) TF_R(29) TF_R(16) TF_R(24)
  x0 += ks1; x1 += ks2 + 4u;
  TF_R(13) TF_R(15) TF_R(26) TF_R(6)
  x0 += ks2; x1 += ks0 + 5u;
#undef TF_R
  return x0 ^ x1;
}

__device__ __forceinline__ float waveReduceSum(float v) {
#pragma unroll
  for (int off = 32; off > 0; off >>= 1) v += __shfl_down(v, off, 64);
  return v;
}

// Deterministic block-wide exclusive scan over 1024 threads (16 waves).
// All threads must call; returns exclusive prefix; *total gets block sum.
// Entry barrier protects swt/soffs reuse across consecutive calls.
__device__ __forceinline__ uint32_t blockExclScan1024(
    uint32_t v, volatile uint32_t* swt, volatile uint32_t* soffs,
    uint32_t* total) {
  const int tid = threadIdx.x;
  const int lane = tid & 63;
  const int wv = tid >> 6;
  __syncthreads();
  uint32_t incl = v;
#pragma unroll
  for (int off = 1; off < 64; off <<= 1) {
    uint32_t u = __shfl_up(incl, off, 64);
    if (lane >= off) incl += u;
  }
  if (lane == 63) swt[wv] = incl;
  __syncthreads();
  if (tid < 16) {
    uint32_t t = swt[tid], s = t;
#pragma unroll
    for (int off = 1; off < 16; off <<= 1) {
      uint32_t u = __shfl_up(s, off, 64);
      if (lane >= off) s += u;
    }
    soffs[tid] = s - t;
  }
  __syncthreads();
  *total = soffs[15] + swt[15];
  return soffs[wv] + incl - v;
}

// ---------------------------------------------------------------------------
// K1: score. 256 blocks x 1024 thr; block = (batch b, quarter q). Each block
// hashes ONLY its quarter (4 px/thread), stores 23-bit u-keys (+1; 0=masked)
// to global ubits, and its per-quarter 512-bucket histogram (plain stores —
// no cross-block zero/atomic needed on poisoned workspace). Also zeroes out.
// ---------------------------------------------------------------------------
__global__ __launch_bounds__(1024) void score_kernel(
    const float4* __restrict__ real4,
    uint32_t* __restrict__ ubits,
    uint32_t* __restrict__ histg,
    float* __restrict__ out) {
  const int bq = blockIdx.x;
  const int b = bq >> 2, q = bq & 3;
  const int tid = threadIdx.x;
  __shared__ uint32_t hist[512];

  if (bq == 0 && tid == 0) out[0] = 0.0f;
  if (tid < 512) hist[tid] = 0u;

  float4 im = real4[(size_t)b * 4096 + q * 1024 + tid];
  uint32_t base = (uint32_t)(b * NPIX + q * 4096) + (uint32_t)(tid << 2);
  uint32_t u0 = (im.x <= 0.99f) ? ((threefry_bits(base + 0u) >> 9) + 1u) : 0u;
  uint32_t u1 = (im.y <= 0.99f) ? ((threefry_bits(base + 1u) >> 9) + 1u) : 0u;
  uint32_t u2 = (im.z <= 0.99f) ? ((threefry_bits(base + 2u) >> 9) + 1u) : 0u;
  uint32_t u3 = (im.w <= 0.99f) ? ((threefry_bits(base + 3u) >> 9) + 1u) : 0u;

  uint4 st; st.x = u0; st.y = u1; st.z = u2; st.w = u3;
  ((uint4*)ubits)[(size_t)b * 4096 + q * 1024 + tid] = st;

  __syncthreads();   // hist zeroed
  if (u0) atomicAdd(&hist[(u0 - 1u) >> 14], 1u);
  if (u1) atomicAdd(&hist[(u1 - 1u) >> 14], 1u);
  if (u2) atomicAdd(&hist[(u2 - 1u) >> 14], 1u);
  if (u3) atomicAdd(&hist[(u3 - 1u) >> 14], 1u);
  __syncthreads();   // atomics done
  if (tid < 512) histg[(size_t)bq * 512 + tid] = hist[tid];
}

// ---------------------------------------------------------------------------
// K2: select + chamfer. 256 blocks x 1024 thr; block = (batch b, quarter q).
// Reads the batch's ubits (L2) + per-quarter hists, redundantly computes the
// batch's selection with the verified deterministic scan-compaction into LDS
// sp4, then runs the verified chamfer on its quarter slice.
// Round-5 slimming: no real4 bulk reload (depth gathered scalar at emit, ~1
// per thread from L2); class loop emits bitmasks; sparse ffs-driven emit.
// ---------------------------------------------------------------------------
__global__ __launch_bounds__(1024) void chamsel_kernel(
    const float* __restrict__ real,
    const float* __restrict__ verts,
    const float* __restrict__ center,
    const float* __restrict__ M,
    const float* __restrict__ cube,
    const uint32_t* __restrict__ ubits,
    const uint32_t* __restrict__ histg,
    float* __restrict__ out) {
  const int bq = blockIdx.x;
  const int b = bq >> 2, q = bq & 3;
  const int tid = threadIdx.x;
  const int lane = tid & 63;
  const int wv = tid >> 6;

  // LDS layout
  __shared__ __align__(16) uint8_t shbuf[49312];
  float4*   sv4    = (float4*)shbuf;               // 778*16  = 12448
  float4*   sp4    = (float4*)(shbuf + 12448);     // 1024*16 = 16384
  float*    fbuf   = (float*)(shbuf + 28832);      // 16*256*4= 16384
  uint64_t* cand   = (uint64_t*)(shbuf + 45216);   // 512*8   = 4096
  __shared__ uint32_t wt[8], offs[8];
  __shared__ uint32_t swt[16], soffs[16];
  __shared__ float sh_minv[6], sh_c[3], sh_hb[3];
  __shared__ uint32_t sh_bstar, sh_above;
  __shared__ float red[16];

  if (tid == 0) {
    const float* m = M + (size_t)b * 9;
    float m00=m[0], m01=m[1], m02=m[2];
    float m10=m[3], m11=m[4], m12=m[5];
    float m20=m[6], m21=m[7], m22=m[8];
    float c00 = m11*m22 - m12*m21;
    float c10 = m12*m20 - m10*m22;
    float c20 = m10*m21 - m11*m20;
    float det = m00*c00 + m01*c10 + m02*c20;
    float id = 1.0f / det;
    sh_minv[0] = c00 * id;
    sh_minv[1] = (m02*m21 - m01*m22) * id;
    sh_minv[2] = (m01*m12 - m02*m11) * id;
    sh_minv[3] = c10 * id;
    sh_minv[4] = (m00*m22 - m02*m20) * id;
    sh_minv[5] = (m02*m10 - m00*m12) * id;
    sh_c[0] = center[b*3+0]; sh_c[1] = center[b*3+1]; sh_c[2] = center[b*3+2];
    sh_hb[0] = cube[b*3+0]*0.5f; sh_hb[1] = cube[b*3+1]*0.5f; sh_hb[2] = cube[b*3+2]*0.5f;
  }

  // Stage verts (used by chamfer; also provides |v|^2 for B-dir sums).
  const float* vb = verts + (size_t)b * NV * 3;
  for (int v = tid; v < NV; v += 1024) {
    float x = vb[v*3], y = vb[v*3+1], z = vb[v*3+2];
    float4 t;
    t.x = -2.0f*x; t.y = -2.0f*y; t.z = -2.0f*z; t.w = x*x + y*y + z*z;
    sv4[v] = t;
  }

  // Load full-batch u-keys: 16 px/thread, p = e4*4096 + tid*4 + c.
  uint32_t uv[16];
  const uint4* ub4 = (const uint4*)ubits + (size_t)b * (NPIX / 4);
#pragma unroll
  for (int e4 = 0; e4 < 4; ++e4) {
    uint4 uu = ub4[e4 * 1024 + tid];
    uv[e4*4+0] = uu.x; uv[e4*4+1] = uu.y; uv[e4*4+2] = uu.z; uv[e4*4+3] = uu.w;
  }

  // Suffix scan over summed 512-bucket hist -> bstar, count above.
  uint32_t cnt = 0, sfx = 0;
  if (tid < 512) {
    const uint32_t* hp = histg + (size_t)(b << 2) * 512 + tid;
    cnt = hp[0] + hp[512] + hp[1024] + hp[1536];
    sfx = cnt;
#pragma unroll
    for (int off = 1; off < 64; off <<= 1) {
      uint32_t u = __shfl_down(sfx, off, 64);
      if (lane + off < 64) sfx += u;
    }
    if (lane == 0) wt[wv] = sfx;
  }
  __syncthreads();
  if (tid < 8) {
    uint32_t t = wt[tid], s = t;
#pragma unroll
    for (int off = 1; off < 8; off <<= 1) {
      uint32_t u = __shfl_down(s, off, 64);
      if (tid + off < 8) s += u;
    }
    offs[tid] = s - t;
  }
  __syncthreads();
  if (tid < 512) {
    uint32_t tot = sfx + offs[wv];   // keys in buckets >= tid
    uint32_t above = tot - cnt;      // keys in buckets >  tid
    if (tot >= SAMPLE && above < SAMPLE && cnt > 0) {
      sh_bstar = (uint32_t)tid;
      sh_above = above;
    }
  }
  __syncthreads();
  const int bstar = (int)sh_bstar;
  const uint32_t above = sh_above;
  const uint32_t kneed = SAMPLE - above;

  // Emit helper: gather depth scalar from L2-resident image, transform,
  // stage into LDS sp4 as (-2x', -2y', -2z', |p'|^2).
  const float* rb = real + (size_t)b * NPIX;
  auto emit = [&](int p, uint32_t slot) {
    float depth01 = rb[p];
    int i = p >> 7, j = p & 127;
    float tj = (2.0f * (float)j) / 127.0f - 1.0f;
    float ti = (2.0f * (float)i) / 127.0f - 1.0f;
    float u0 = (tj + 1.0f) * 64.0f;
    float u1 = (ti + 1.0f) * 64.0f;
    float d  = depth01 * sh_hb[2] + sh_c[2];
    float w0 = sh_minv[0]*u0 + sh_minv[1]*u1 + sh_minv[2];
    float w1 = sh_minv[3]*u0 + sh_minv[4]*u1 + sh_minv[5];
    float x = (w0 - 320.0f) * d / 588.03f;
    float y = (w1 - 240.0f) * d / 587.07f;
    float ox = (x - sh_c[0]) / sh_hb[0];
    float oy = (y - sh_c[1]) / sh_hb[1];
    float oz = (d - sh_c[2]) / sh_hb[2];
    float4 t;
    t.x = -2.0f*ox; t.y = -2.0f*oy; t.z = -2.0f*oz;
    t.w = ox*ox + oy*oy + oz*oz;
    sp4[slot] = t;
  };

  // Class bitmasks: bit e set iff element e is hi (> bstar) / eq (== bstar).
  uint32_t mhi = 0u, meq = 0u;
#pragma unroll
  for (int e = 0; e < 16; ++e) {
    uint32_t v = uv[e];
    int bk = v ? (int)((v - 1u) >> 14) : -1;
    mhi |= (bk > bstar) ? (1u << e) : 0u;
    meq |= (bk == bstar) ? (1u << e) : 0u;
  }
  uint32_t htot, etot;
  uint32_t hoff = blockExclScan1024(__popc(mhi), swt, soffs, &htot);
  uint32_t eoff = blockExclScan1024(__popc(meq), swt, soffs, &etot);

  // Sparse ffs-driven emits (avg ~1 hi + ~0.03 eq per thread).
  {
    uint32_t mm = mhi, h = hoff;
    while (mm) {
      int e = __ffs(mm) - 1; mm &= mm - 1u;
      int p = (e >> 2) * 4096 + (tid << 2) + (e & 3);
      emit(p, h++);
    }
    mm = meq; uint32_t eo = eoff;
    while (mm) {
      int e = __ffs(mm) - 1; mm &= mm - 1u;
      int p = (e >> 2) * 4096 + (tid << 2) + (e & 3);
      if (eo < 512u) cand[eo] = ((uint64_t)uv[e] << 14) | (uint64_t)(16383 - p);
      eo++;
    }
  }
  __syncthreads();   // cand + hi-emits complete

  // Boundary-bucket rank-select (parallel: one candidate per thread).
  uint32_t c = etot; if (c > 512u) c = 512u;
  uint32_t selbit = 0; uint64_t ki = 0;
  if (tid < (int)c) {
    ki = cand[tid];
    uint32_t rank = 0;
    for (uint32_t j2 = 0; j2 < c; ++j2) rank += (cand[j2] > ki) ? 1u : 0u;
    selbit = (rank < kneed) ? 1u : 0u;   // keys unique -> exactly kneed
  }
  uint32_t stot;
  uint32_t soff2 = blockExclScan1024(selbit, swt, soffs, &stot);
  if (selbit) {
    int p = 16383 - (int)(ki & 0x3FFFull);
    emit(p, above + soff2);
  }
  __syncthreads();   // sp4[0..1023] complete and identical across q-blocks

  // ---- Chamfer (verified structure) ----
  float val = 0.0f;
  const int sub = tid & 63;
  const int seg16 = tid >> 6;

  // dir A: points q*256..q*256+255 vs ALL verts; 16-way vert split.
  {
    float px[4], py[4], pz[4], mnA[4];
#pragma unroll
    for (int j = 0; j < 4; ++j) {
      float4 sp = sp4[q * 256 + j * 64 + sub];
      px[j] = -0.5f * sp.x; py[j] = -0.5f * sp.y; pz[j] = -0.5f * sp.z;
      mnA[j] = INFINITY;
    }
    int vs = seg16 * 49, ve = vs + 49; if (ve > NV) ve = NV;
    for (int v = vs; v < ve; ++v) {
      float4 vv = sv4[v];                       // wave-uniform broadcast
#pragma unroll
      for (int j = 0; j < 4; ++j) {
        float t = fmaf(pz[j], vv.z, fmaf(py[j], vv.y, fmaf(px[j], vv.x, vv.w)));
        mnA[j] = fminf(mnA[j], t);
      }
    }
#pragma unroll
    for (int j = 0; j < 4; ++j) fbuf[seg16 * 256 + j * 64 + sub] = mnA[j];
  }
  __syncthreads();
  if (tid < 256) {
    float m = fbuf[tid];
#pragma unroll
    for (int s2 = 1; s2 < 16; ++s2) m = fminf(m, fbuf[s2 * 256 + tid]);
    val += (m + sp4[q * 256 + tid].w) * A_SCALE;
  }
  __syncthreads();

  // dir B: verts q*195.. vs ALL points; 16-way point split.
  {
    const int vbase = q * 195;
    int nsl = NV - vbase; if (nsl > 195) nsl = 195;
    float vx[4], vy[4], vz[4], mnB[4];
#pragma unroll
    for (int j = 0; j < 4; ++j) {
      int vloc = j * 64 + sub;
      int vi = (vloc < nsl) ? (vbase + vloc) : 0;
      float4 sv = sv4[vi];
      vx[j] = -0.5f * sv.x; vy[j] = -0.5f * sv.y; vz[j] = -0.5f * sv.z;
      mnB[j] = INFINITY;
    }
    int is = seg16 * 64;
    for (int i = 0; i < 64; ++i) {
      float4 pp = sp4[is + i];                  // wave-uniform broadcast
#pragma unroll
      for (int j = 0; j < 4; ++j) {
        float t = fmaf(vz[j], pp.z, fmaf(vy[j], pp.y, fmaf(vx[j], pp.x, pp.w)));
        mnB[j] = fminf(mnB[j], t);
      }
    }
#pragma unroll
    for (int j = 0; j < 4; ++j) fbuf[seg16 * 256 + j * 64 + sub] = mnB[j];
  }
  __syncthreads();
  {
    const int vbase = q * 195;
    int nsl = NV - vbase; if (nsl > 195) nsl = 195;
    if (tid < nsl) {
      float m = fbuf[tid];
#pragma unroll
      for (int s2 = 1; s2 < 16; ++s2) m = fminf(m, fbuf[s2 * 256 + tid]);
      val += (m + sv4[vbase + tid].w) * B_SCALE;
    }
  }

  float r = waveReduceSum(val);
  if (lane == 0) red[wv] = r;
  __syncthreads();
  if (tid == 0) {
    float s = 0.0f;
#pragma unroll
    for (int i = 0; i < 16; ++i) s += red[i];
    atomicAdd(out, s);
  }
}

// ===========================================================================
// Fallback: verified round-3 mega kernel (self-contained select, no ws).
// ===========================================================================
__global__ __launch_bounds__(1024) void mega_kernel(
    const float4* __restrict__ real4,
    const float* __restrict__ verts,
    const float* __restrict__ center,
    const float* __restrict__ M,
    const float* __restrict__ cube,
    float* __restrict__ out) {
  const int bq = blockIdx.x;
  const int b = bq >> 2, q = bq & 3;
  const int tid = threadIdx.x;
  const int lane = tid & 63;
  const int wv = tid >> 6;

  __shared__ __align__(16) uint8_t shbuf[53408];
  float4*   sv4    = (float4*)shbuf;
  float4*   sp4    = (float4*)(shbuf + 12448);
  float*    fbuf   = (float*)(shbuf + 28832);
  uint32_t* hist   = (uint32_t*)(shbuf + 45216);
  uint64_t* cand   = (uint64_t*)(shbuf + 47264);
  float*    candrv = (float*)(shbuf + 51360);
  __shared__ uint32_t wt[8], offs[8];
  __shared__ uint32_t swt[16], soffs[16];
  __shared__ float sh_minv[6], sh_c[3], sh_hb[3];
  __shared__ uint32_t sh_bstar, sh_above;
  __shared__ float red[16];

  if (tid == 0) {
    const float* m = M + (size_t)b * 9;
    float m00=m[0], m01=m[1], m02=m[2];
    float m10=m[3], m11=m[4], m12=m[5];
    float m20=m[6], m21=m[7], m22=m[8];
    float c00 = m11*m22 - m12*m21;
    float c10 = m12*m20 - m10*m22;
    float c20 = m10*m21 - m11*m20;
    float det = m00*c00 + m01*c10 + m02*c20;
    float id = 1.0f / det;
    sh_minv[0] = c00 * id;
    sh_minv[1] = (m02*m21 - m01*m22) * id;
    sh_minv[2] = (m01*m12 - m02*m11) * id;
    sh_minv[3] = c10 * id;
    sh_minv[4] = (m00*m22 - m02*m20) * id;
    sh_minv[5] = (m02*m10 - m00*m12) * id;
    sh_c[0] = center[b*3+0]; sh_c[1] = center[b*3+1]; sh_c[2] = center[b*3+2];
    sh_hb[0] = cube[b*3+0]*0.5f; sh_hb[1] = cube[b*3+1]*0.5f; sh_hb[2] = cube[b*3+2]*0.5f;
  }
  if (tid < 512) hist[tid] = 0u;

  const float* vb = verts + (size_t)b * NV * 3;
  for (int v = tid; v < NV; v += 1024) {
    float x = vb[v*3], y = vb[v*3+1], z = vb[v*3+2];
    float4 t;
    t.x = -2.0f*x; t.y = -2.0f*y; t.z = -2.0f*z; t.w = x*x + y*y + z*z;
    sv4[v] = t;
  }

  uint32_t uv[16];
  float    rvv[16];
  const float4* rb4 = real4 + (size_t)b * (NPIX / 4);
#pragma unroll
  for (int e4 = 0; e4 < 4; ++e4) {
    float4 im = rb4[e4 * 1024 + tid];
    uint32_t base = (uint32_t)(b * NPIX + e4 * 4096) + (uint32_t)(tid << 2);
    rvv[e4*4+0] = im.x; rvv[e4*4+1] = im.y; rvv[e4*4+2] = im.z; rvv[e4*4+3] = im.w;
    uv[e4*4+0] = (im.x <= 0.99f) ? ((threefry_bits(base + 0u) >> 9) + 1u) : 0u;
    uv[e4*4+1] = (im.y <= 0.99f) ? ((threefry_bits(base + 1u) >> 9) + 1u) : 0u;
    uv[e4*4+2] = (im.z <= 0.99f) ? ((threefry_bits(base + 2u) >> 9) + 1u) : 0u;
    uv[e4*4+3] = (im.w <= 0.99f) ? ((threefry_bits(base + 3u) >> 9) + 1u) : 0u;
  }
  __syncthreads();

#pragma unroll
  for (int e = 0; e < 16; ++e)
    if (uv[e]) atomicAdd(&hist[(uv[e] - 1u) >> 14], 1u);
  __syncthreads();

  uint32_t cnt = 0, sfx = 0;
  if (tid < 512) {
    cnt = hist[tid];
    sfx = cnt;
#pragma unroll
    for (int off = 1; off < 64; off <<= 1) {
      uint32_t u = __shfl_down(sfx, off, 64);
      if (lane + off < 64) sfx += u;
    }
    if (lane == 0) wt[wv] = sfx;
  }
  __syncthreads();
  if (tid < 8) {
    uint32_t t = wt[tid], s = t;
#pragma unroll
    for (int off = 1; off < 8; off <<= 1) {
      uint32_t u = __shfl_down(s, off, 64);
      if (tid + off < 8) s += u;
    }
    offs[tid] = s - t;
  }
  __syncthreads();
  if (tid < 512) {
    uint32_t tot = sfx + offs[wv];
    uint32_t above = tot - cnt;
    if (tot >= SAMPLE && above < SAMPLE && cnt > 0) {
      sh_bstar = (uint32_t)tid;
      sh_above = above;
    }
  }
  __syncthreads();
  const int bstar = (int)sh_bstar;
  const uint32_t above = sh_above;
  const uint32_t kneed = SAMPLE - above;

  auto emit = [&](int p, float depth01, uint32_t slot) {
    int i = p >> 7, j = p & 127;
    float tj = (2.0f * (float)j) / 127.0f - 1.0f;
    float ti = (2.0f * (float)i) / 127.0f - 1.0f;
    float u0 = (tj + 1.0f) * 64.0f;
    float u1 = (ti + 1.0f) * 64.0f;
    float d  = depth01 * sh_hb[2] + sh_c[2];
    float w0 = sh_minv[0]*u0 + sh_minv[1]*u1 + sh_minv[2];
    float w1 = sh_minv[3]*u0 + sh_minv[4]*u1 + sh_minv[5];
    float x = (w0 - 320.0f) * d / 588.03f;
    float y = (w1 - 240.0f) * d / 587.07f;
    float ox = (x - sh_c[0]) / sh_hb[0];
    float oy = (y - sh_c[1]) / sh_hb[1];
    float oz = (d - sh_c[2]) / sh_hb[2];
    float4 t;
    t.x = -2.0f*ox; t.y = -2.0f*oy; t.z = -2.0f*oz;
    t.w = ox*ox + oy*oy + oz*oz;
    sp4[slot] = t;
  };

  uint32_t ch = 0, ce = 0;
#pragma unroll
  for (int e = 0; e < 16; ++e) {
    int bk = uv[e] ? (int)((uv[e] - 1u) >> 14) : -1;
    ch += (bk > bstar) ? 1u : 0u;
    ce += (bk == bstar) ? 1u : 0u;
  }
  uint32_t htot, etot;
  uint32_t hoff = blockExclScan1024(ch, swt, soffs, &htot);
  uint32_t eoff = blockExclScan1024(ce, swt, soffs, &etot);

  {
    uint32_t h = hoff, eo = eoff;
#pragma unroll
    for (int e = 0; e < 16; ++e) {
      uint32_t v = uv[e];
      int bk = v ? (int)((v - 1u) >> 14) : -1;
      int p = (e >> 2) * 4096 + (tid << 2) + (e & 3);
      if (bk > bstar) {
        emit(p, rvv[e], h++);
      } else if (bk == bstar) {
        if (eo < 512u) {
          cand[eo] = ((uint64_t)v << 14) | (uint64_t)(16383 - p);
          candrv[eo] = rvv[e];
        }
        eo++;
      }
    }
  }
  __syncthreads();

  uint32_t c = etot; if (c > 512u) c = 512u;
  uint32_t selbit = 0; uint64_t ki = 0;
  if (tid < (int)c) {
    ki = cand[tid];
    uint32_t rank = 0;
    for (uint32_t j2 = 0; j2 < c; ++j2) rank += (cand[j2] > ki) ? 1u : 0u;
    selbit = (rank < kneed) ? 1u : 0u;
  }
  uint32_t stot;
  uint32_t soff2 = blockExclScan1024(selbit, swt, soffs, &stot);
  if (selbit) {
    int p = 16383 - (int)(ki & 0x3FFFull);
    emit(p, candrv[tid], above + soff2);
  }
  __syncthreads();

  float val = 0.0f;
  const int sub = tid & 63;
  const int seg16 = tid >> 6;

  {
    float px[4], py[4], pz[4], mnA[4];
#pragma unroll
    for (int j = 0; j < 4; ++j) {
      float4 sp = sp4[q * 256 + j * 64 + sub];
      px[j] = -0.5f * sp.x; py[j] = -0.5f * sp.y; pz[j] = -0.5f * sp.z;
      mnA[j] = INFINITY;
    }
    int vs = seg16 * 49, ve = vs + 49; if (ve > NV) ve = NV;
    for (int v = vs; v < ve; ++v) {
      float4 vv = sv4[v];
#pragma unroll
      for (int j = 0; j < 4; ++j) {
        float t = fmaf(pz[j], vv.z, fmaf(py[j], vv.y, fmaf(px[j], vv.x, vv.w)));
        mnA[j] = fminf(mnA[j], t);
      }
    }
#pragma unroll
    for (int j = 0; j < 4; ++j) fbuf[seg16 * 256 + j * 64 + sub] = mnA[j];
  }
  __syncthreads();
  if (tid < 256) {
    float m = fbuf[tid];
#pragma unroll
    for (int s2 = 1; s2 < 16; ++s2) m = fminf(m, fbuf[s2 * 256 + tid]);
    val += (m + sp4[q * 256 + tid].w) * A_SCALE;
  }
  __syncthreads();

  {
    const int vbase = q * 195;
    int nsl = NV - vbase; if (nsl > 195) nsl = 195;
    float vx[4], vy[4], vz[4], mnB[4];
#pragma unroll
    for (int j = 0; j < 4; ++j) {
      int vloc = j * 64 + sub;
      int vi = (vloc < nsl) ? (vbase + vloc) : 0;
      float4 sv = sv4[vi];
      vx[j] = -0.5f * sv.x; vy[j] = -0.5f * sv.y; vz[j] = -0.5f * sv.z;
      mnB[j] = INFINITY;
    }
    int is = seg16 * 64;
    for (int i = 0; i < 64; ++i) {
      float4 pp = sp4[is + i];
#pragma unroll
      for (int j = 0; j < 4; ++j) {
        float t = fmaf(vz[j], pp.z, fmaf(vy[j], pp.y, fmaf(vx[j], pp.x, pp.w)));
        mnB[j] = fminf(mnB[j], t);
      }
    }
#pragma unroll
    for (int j = 0; j < 4; ++j) fbuf[seg16 * 256 + j * 64 + sub] = mnB[j];
  }
  __syncthreads();
  {
    const int vbase = q * 195;
    int nsl = NV - vbase; if (nsl > 195) nsl = 195;
    if (tid < nsl) {
      float m = fbuf[tid];
#pragma unroll
      for (int s2 = 1; s2 < 16; ++s2) m = fminf(m, fbuf[s2 * 256 + tid]);
      val += (m + sv4[vbase + tid].w) * B_SCALE;
    }
  }

  float r = waveReduceSum(val);
  if (lane == 0) red[wv] = r;
  __syncthreads();
  if (tid == 0) {
    float s = 0.0f;
#pragma unroll
    for (int i = 0; i < 16; ++i) s += red[i];
    atomicAdd(out, s);
  }
}

extern "C" void kernel_launch(void* const* d_in, const int* in_sizes, int n_in,
                              void* d_out, int out_size, void* d_ws, size_t ws_size,
                              hipStream_t stream) {
  const float* real   = (const float*)d_in[0];
  // d_in[1] = synth (unused), d_in[3] = faces (unused)
  const float* verts  = (const float*)d_in[2];
  const float* center = (const float*)d_in[4];
  const float* M      = (const float*)d_in[5];
  const float* cube   = (const float*)d_in[6];
  float* out = (float*)d_out;

  if (ws_size >= (size_t)WS_NEEDED) {
    uint8_t* w = (uint8_t*)d_ws;
    uint32_t* ubits = (uint32_t*)(w + WS_UBITS);
    uint32_t* histg = (uint32_t*)(w + WS_HISTG);
    score_kernel<<<dim3(BATCH * 4), dim3(1024), 0, stream>>>(
        (const float4*)real, ubits, histg, out);
    chamsel_kernel<<<dim3(BATCH * 4), dim3(1024), 0, stream>>>(
        real, verts, center, M, cube, ubits, histg, out);
  } else {
    hipMemsetAsync(out, 0, sizeof(float), stream);
    mega_kernel<<<dim3(BATCH * 4), dim3(1024), 0, stream>>>(
        (const float4*)real, verts, center, M, cube, out);
  }
}

// Round 6
// 96.351 us; speedup vs baseline: 2.6213x; 1.0125x over previous
//
#include <hip/hip_runtime.h>
#include <stdint.h>
#include <math.h>

#define NPIX   16384
#define SAMPLE 1024
#define NV     778
#define BATCH  64

#define A_SCALE (1.0f / (float)(BATCH * SAMPLE))
#define B_SCALE (1.0f / (float)(BATCH * NV))

// Workspace layout (bytes)
#define WS_UBITS  0u          // 64*16384*4 = 4194304
#define WS_HISTG  4194304u    // 256*512*4  = 524288
#define WS_NEEDED 4718592u

// ---------------------------------------------------------------------------
// Threefry-2x32, 20 rounds — matches jax._src.prng lowering exactly.
// ---------------------------------------------------------------------------
__device__ __forceinline__ uint32_t rotl32(uint32_t v, int r) {
  return (v << r) | (v >> (32 - r));
}

__device__ __forceinline__ uint32_t threefry_bits(uint32_t g) {
  // key(1) = (0,1); partitionable path: x0 = counts_hi = 0, x1 = g; out h0^h1.
  uint32_t ks0 = 0u, ks1 = 1u;
  uint32_t ks2 = ks0 ^ ks1 ^ 0x1BD11BDAu;
  uint32_t x0 = 0u + ks0, x1 = g + ks1;
#define TF_R(r) { x0 += x1; x1 = rotl32(x1, (r)); x1 ^= x0; }
  TF_R(13) TF_R(15) TF_R(26) TF_R(6)
  x0 += ks1; x1 += ks2 + 1u;
  TF_R(17) TF_R(29) TF_R(16) TF_R(24)
  x0 += ks2; x1 += ks0 + 2u;
  TF_R(13) TF_R(15) TF_R(26) TF_R(6)
  x0 += ks0; x1 += ks1 + 3u;
  TF_R(17) TF_R(29) TF_R(16) TF_R(24)
  x0 += ks1; x1 += ks2 + 4u;
  TF_R(13) TF_R(15) TF_R(26) TF_R(6)
  x0 += ks2; x1 += ks0 + 5u;
#undef TF_R
  return x0 ^ x1;
}

__device__ __forceinline__ float waveReduceSum(float v) {
#pragma unroll
  for (int off = 32; off > 0; off >>= 1) v += __shfl_down(v, off, 64);
  return v;
}

// Deterministic block-wide exclusive scan over 1024 threads (16 waves).
// All threads must call; returns exclusive prefix; *total gets block sum.
// Entry barrier protects swt/soffs reuse across consecutive calls.
__device__ __forceinline__ uint32_t blockExclScan1024(
    uint32_t v, volatile uint32_t* swt, volatile uint32_t* soffs,
    uint32_t* total) {
  const int tid = threadIdx.x;
  const int lane = tid & 63;
  const int wv = tid >> 6;
  __syncthreads();
  uint32_t incl = v;
#pragma unroll
  for (int off = 1; off < 64; off <<= 1) {
    uint32_t u = __shfl_up(incl, off, 64);
    if (lane >= off) incl += u;
  }
  if (lane == 63) swt[wv] = incl;
  __syncthreads();
  if (tid < 16) {
    uint32_t t = swt[tid], s = t;
#pragma unroll
    for (int off = 1; off < 16; off <<= 1) {
      uint32_t u = __shfl_up(s, off, 64);
      if (lane >= off) s += u;
    }
    soffs[tid] = s - t;
  }
  __syncthreads();
  *total = soffs[15] + swt[15];
  return soffs[wv] + incl - v;
}

// ---------------------------------------------------------------------------
// K1: score. 256 blocks x 1024 thr; block = (batch b, quarter q). Each block
// hashes ONLY its quarter (4 px/thread), stores 23-bit u-keys (+1; 0=masked)
// to global ubits, and its per-quarter 512-bucket histogram (plain stores —
// no cross-block zero/atomic needed on poisoned workspace). Also zeroes out.
// ---------------------------------------------------------------------------
__global__ __launch_bounds__(1024) void score_kernel(
    const float4* __restrict__ real4,
    uint32_t* __restrict__ ubits,
    uint32_t* __restrict__ histg,
    float* __restrict__ out) {
  const int bq = blockIdx.x;
  const int b = bq >> 2, q = bq & 3;
  const int tid = threadIdx.x;
  __shared__ uint32_t hist[512];

  if (bq == 0 && tid == 0) out[0] = 0.0f;
  if (tid < 512) hist[tid] = 0u;

  float4 im = real4[(size_t)b * 4096 + q * 1024 + tid];
  uint32_t base = (uint32_t)(b * NPIX + q * 4096) + (uint32_t)(tid << 2);
  uint32_t u0 = (im.x <= 0.99f) ? ((threefry_bits(base + 0u) >> 9) + 1u) : 0u;
  uint32_t u1 = (im.y <= 0.99f) ? ((threefry_bits(base + 1u) >> 9) + 1u) : 0u;
  uint32_t u2 = (im.z <= 0.99f) ? ((threefry_bits(base + 2u) >> 9) + 1u) : 0u;
  uint32_t u3 = (im.w <= 0.99f) ? ((threefry_bits(base + 3u) >> 9) + 1u) : 0u;

  uint4 st; st.x = u0; st.y = u1; st.z = u2; st.w = u3;
  ((uint4*)ubits)[(size_t)b * 4096 + q * 1024 + tid] = st;

  __syncthreads();   // hist zeroed
  if (u0) atomicAdd(&hist[(u0 - 1u) >> 14], 1u);
  if (u1) atomicAdd(&hist[(u1 - 1u) >> 14], 1u);
  if (u2) atomicAdd(&hist[(u2 - 1u) >> 14], 1u);
  if (u3) atomicAdd(&hist[(u3 - 1u) >> 14], 1u);
  __syncthreads();   // atomics done
  if (tid < 512) histg[(size_t)bq * 512 + tid] = hist[tid];
}

// ---------------------------------------------------------------------------
// K2: select + chamfer. 256 blocks x 1024 thr; block = (batch b, quarter q).
// Reads the batch's ubits (L2) + per-quarter hists, redundantly computes the
// batch's selection with the verified deterministic scan-compaction into LDS
// sp4, then runs the verified chamfer on its quarter slice.
// Round-6: single PACKED scan for hi|eq counts (hi bits 0-15, eq 16-31;
// totals <= 16384 so no overflow), unroll-4 chamfer loops,
// __launch_bounds__(1024,8) pins VGPR <= 64 for 2 blocks/CU.
// ---------------------------------------------------------------------------
__global__ __launch_bounds__(1024, 8) void chamsel_kernel(
    const float* __restrict__ real,
    const float* __restrict__ verts,
    const float* __restrict__ center,
    const float* __restrict__ M,
    const float* __restrict__ cube,
    const uint32_t* __restrict__ ubits,
    const uint32_t* __restrict__ histg,
    float* __restrict__ out) {
  const int bq = blockIdx.x;
  const int b = bq >> 2, q = bq & 3;
  const int tid = threadIdx.x;
  const int lane = tid & 63;
  const int wv = tid >> 6;

  // LDS layout
  __shared__ __align__(16) uint8_t shbuf[49312];
  float4*   sv4    = (float4*)shbuf;               // 778*16  = 12448
  float4*   sp4    = (float4*)(shbuf + 12448);     // 1024*16 = 16384
  float*    fbuf   = (float*)(shbuf + 28832);      // 16*256*4= 16384
  uint64_t* cand   = (uint64_t*)(shbuf + 45216);   // 512*8   = 4096
  __shared__ uint32_t wt[8], offs[8];
  __shared__ uint32_t swt[16], soffs[16];
  __shared__ float sh_minv[6], sh_c[3], sh_hb[3];
  __shared__ uint32_t sh_bstar, sh_above;
  __shared__ float red[16];

  if (tid == 0) {
    const float* m = M + (size_t)b * 9;
    float m00=m[0], m01=m[1], m02=m[2];
    float m10=m[3], m11=m[4], m12=m[5];
    float m20=m[6], m21=m[7], m22=m[8];
    float c00 = m11*m22 - m12*m21;
    float c10 = m12*m20 - m10*m22;
    float c20 = m10*m21 - m11*m20;
    float det = m00*c00 + m01*c10 + m02*c20;
    float id = 1.0f / det;
    sh_minv[0] = c00 * id;
    sh_minv[1] = (m02*m21 - m01*m22) * id;
    sh_minv[2] = (m01*m12 - m02*m11) * id;
    sh_minv[3] = c10 * id;
    sh_minv[4] = (m00*m22 - m02*m20) * id;
    sh_minv[5] = (m02*m10 - m00*m12) * id;
    sh_c[0] = center[b*3+0]; sh_c[1] = center[b*3+1]; sh_c[2] = center[b*3+2];
    sh_hb[0] = cube[b*3+0]*0.5f; sh_hb[1] = cube[b*3+1]*0.5f; sh_hb[2] = cube[b*3+2]*0.5f;
  }

  // Stage verts (used by chamfer; also provides |v|^2 for B-dir sums).
  const float* vb = verts + (size_t)b * NV * 3;
  for (int v = tid; v < NV; v += 1024) {
    float x = vb[v*3], y = vb[v*3+1], z = vb[v*3+2];
    float4 t;
    t.x = -2.0f*x; t.y = -2.0f*y; t.z = -2.0f*z; t.w = x*x + y*y + z*z;
    sv4[v] = t;
  }

  // Load full-batch u-keys: 16 px/thread, p = e4*4096 + tid*4 + c.
  uint32_t uv[16];
  const uint4* ub4 = (const uint4*)ubits + (size_t)b * (NPIX / 4);
#pragma unroll
  for (int e4 = 0; e4 < 4; ++e4) {
    uint4 uu = ub4[e4 * 1024 + tid];
    uv[e4*4+0] = uu.x; uv[e4*4+1] = uu.y; uv[e4*4+2] = uu.z; uv[e4*4+3] = uu.w;
  }

  // Suffix scan over summed 512-bucket hist -> bstar, count above.
  uint32_t cnt = 0, sfx = 0;
  if (tid < 512) {
    const uint32_t* hp = histg + (size_t)(b << 2) * 512 + tid;
    cnt = hp[0] + hp[512] + hp[1024] + hp[1536];
    sfx = cnt;
#pragma unroll
    for (int off = 1; off < 64; off <<= 1) {
      uint32_t u = __shfl_down(sfx, off, 64);
      if (lane + off < 64) sfx += u;
    }
    if (lane == 0) wt[wv] = sfx;
  }
  __syncthreads();
  if (tid < 8) {
    uint32_t t = wt[tid], s = t;
#pragma unroll
    for (int off = 1; off < 8; off <<= 1) {
      uint32_t u = __shfl_down(s, off, 64);
      if (tid + off < 8) s += u;
    }
    offs[tid] = s - t;
  }
  __syncthreads();
  if (tid < 512) {
    uint32_t tot = sfx + offs[wv];   // keys in buckets >= tid
    uint32_t above = tot - cnt;      // keys in buckets >  tid
    if (tot >= SAMPLE && above < SAMPLE && cnt > 0) {
      sh_bstar = (uint32_t)tid;
      sh_above = above;
    }
  }
  __syncthreads();
  const int bstar = (int)sh_bstar;
  const uint32_t above = sh_above;
  const uint32_t kneed = SAMPLE - above;

  // Emit helper: gather depth scalar from L2-resident image, transform,
  // stage into LDS sp4 as (-2x', -2y', -2z', |p'|^2).
  const float* rb = real + (size_t)b * NPIX;
  auto emit = [&](int p, uint32_t slot) {
    float depth01 = rb[p];
    int i = p >> 7, j = p & 127;
    float tj = (2.0f * (float)j) / 127.0f - 1.0f;
    float ti = (2.0f * (float)i) / 127.0f - 1.0f;
    float u0 = (tj + 1.0f) * 64.0f;
    float u1 = (ti + 1.0f) * 64.0f;
    float d  = depth01 * sh_hb[2] + sh_c[2];
    float w0 = sh_minv[0]*u0 + sh_minv[1]*u1 + sh_minv[2];
    float w1 = sh_minv[3]*u0 + sh_minv[4]*u1 + sh_minv[5];
    float x = (w0 - 320.0f) * d / 588.03f;
    float y = (w1 - 240.0f) * d / 587.07f;
    float ox = (x - sh_c[0]) / sh_hb[0];
    float oy = (y - sh_c[1]) / sh_hb[1];
    float oz = (d - sh_c[2]) / sh_hb[2];
    float4 t;
    t.x = -2.0f*ox; t.y = -2.0f*oy; t.z = -2.0f*oz;
    t.w = ox*ox + oy*oy + oz*oz;
    sp4[slot] = t;
  };

  // Class bitmasks: bit e set iff element e is hi (> bstar) / eq (== bstar).
  uint32_t mhi = 0u, meq = 0u;
#pragma unroll
  for (int e = 0; e < 16; ++e) {
    uint32_t v = uv[e];
    int bk = v ? (int)((v - 1u) >> 14) : -1;
    mhi |= (bk > bstar) ? (1u << e) : 0u;
    meq |= (bk == bstar) ? (1u << e) : 0u;
  }
  // Single packed scan: hi count in bits 0-15, eq count in bits 16-31.
  // Block totals <= 16384 each, so fields never overflow.
  uint32_t ptot;
  uint32_t poff = blockExclScan1024(
      (uint32_t)__popc(mhi) | ((uint32_t)__popc(meq) << 16), swt, soffs, &ptot);
  uint32_t hoff = poff & 0xffffu;
  uint32_t eoff = poff >> 16;
  const uint32_t etot = ptot >> 16;

  // Sparse ffs-driven emits (avg ~1 hi + ~0.03 eq per thread).
  {
    uint32_t mm = mhi, h = hoff;
    while (mm) {
      int e = __ffs(mm) - 1; mm &= mm - 1u;
      int p = (e >> 2) * 4096 + (tid << 2) + (e & 3);
      emit(p, h++);
    }
    mm = meq; uint32_t eo = eoff;
    while (mm) {
      int e = __ffs(mm) - 1; mm &= mm - 1u;
      int p = (e >> 2) * 4096 + (tid << 2) + (e & 3);
      if (eo < 512u) cand[eo] = ((uint64_t)uv[e] << 14) | (uint64_t)(16383 - p);
      eo++;
    }
  }
  __syncthreads();   // cand + hi-emits complete

  // Boundary-bucket rank-select (parallel: one candidate per thread).
  uint32_t c = etot; if (c > 512u) c = 512u;
  uint32_t selbit = 0; uint64_t ki = 0;
  if (tid < (int)c) {
    ki = cand[tid];
    uint32_t rank = 0;
    for (uint32_t j2 = 0; j2 < c; ++j2) rank += (cand[j2] > ki) ? 1u : 0u;
    selbit = (rank < kneed) ? 1u : 0u;   // keys unique -> exactly kneed
  }
  uint32_t stot;
  uint32_t soff2 = blockExclScan1024(selbit, swt, soffs, &stot);
  if (selbit) {
    int p = 16383 - (int)(ki & 0x3FFFull);
    emit(p, above + soff2);
  }
  __syncthreads();   // sp4[0..1023] complete and identical across q-blocks

  // ---- Chamfer (verified structure) ----
  float val = 0.0f;
  const int sub = tid & 63;
  const int seg16 = tid >> 6;

  // dir A: points q*256..q*256+255 vs ALL verts; 16-way vert split.
  {
    float px[4], py[4], pz[4], mnA[4];
#pragma unroll
    for (int j = 0; j < 4; ++j) {
      float4 sp = sp4[q * 256 + j * 64 + sub];
      px[j] = -0.5f * sp.x; py[j] = -0.5f * sp.y; pz[j] = -0.5f * sp.z;
      mnA[j] = INFINITY;
    }
    int vs = seg16 * 49, ve = vs + 49; if (ve > NV) ve = NV;
#pragma unroll 4
    for (int v = vs; v < ve; ++v) {
      float4 vv = sv4[v];                       // wave-uniform broadcast
#pragma unroll
      for (int j = 0; j < 4; ++j) {
        float t = fmaf(pz[j], vv.z, fmaf(py[j], vv.y, fmaf(px[j], vv.x, vv.w)));
        mnA[j] = fminf(mnA[j], t);
      }
    }
#pragma unroll
    for (int j = 0; j < 4; ++j) fbuf[seg16 * 256 + j * 64 + sub] = mnA[j];
  }
  __syncthreads();
  if (tid < 256) {
    float m = fbuf[tid];
#pragma unroll
    for (int s2 = 1; s2 < 16; ++s2) m = fminf(m, fbuf[s2 * 256 + tid]);
    val += (m + sp4[q * 256 + tid].w) * A_SCALE;
  }
  __syncthreads();

  // dir B: verts q*195.. vs ALL points; 16-way point split.
  {
    const int vbase = q * 195;
    int nsl = NV - vbase; if (nsl > 195) nsl = 195;
    float vx[4], vy[4], vz[4], mnB[4];
#pragma unroll
    for (int j = 0; j < 4; ++j) {
      int vloc = j * 64 + sub;
      int vi = (vloc < nsl) ? (vbase + vloc) : 0;
      float4 sv = sv4[vi];
      vx[j] = -0.5f * sv.x; vy[j] = -0.5f * sv.y; vz[j] = -0.5f * sv.z;
      mnB[j] = INFINITY;
    }
    int is = seg16 * 64;
#pragma unroll 4
    for (int i = 0; i < 64; ++i) {
      float4 pp = sp4[is + i];                  // wave-uniform broadcast
#pragma unroll
      for (int j = 0; j < 4; ++j) {
        float t = fmaf(vz[j], pp.z, fmaf(vy[j], pp.y, fmaf(vx[j], pp.x, pp.w)));
        mnB[j] = fminf(mnB[j], t);
      }
    }
#pragma unroll
    for (int j = 0; j < 4; ++j) fbuf[seg16 * 256 + j * 64 + sub] = mnB[j];
  }
  __syncthreads();
  {
    const int vbase = q * 195;
    int nsl = NV - vbase; if (nsl > 195) nsl = 195;
    if (tid < nsl) {
      float m = fbuf[tid];
#pragma unroll
      for (int s2 = 1; s2 < 16; ++s2) m = fminf(m, fbuf[s2 * 256 + tid]);
      val += (m + sv4[vbase + tid].w) * B_SCALE;
    }
  }

  float r = waveReduceSum(val);
  if (lane == 0) red[wv] = r;
  __syncthreads();
  if (tid == 0) {
    float s = 0.0f;
#pragma unroll
    for (int i = 0; i < 16; ++i) s += red[i];
    atomicAdd(out, s);
  }
}

// ===========================================================================
// Fallback: verified round-3 mega kernel (self-contained select, no ws).
// ===========================================================================
__global__ __launch_bounds__(1024) void mega_kernel(
    const float4* __restrict__ real4,
    const float* __restrict__ verts,
    const float* __restrict__ center,
    const float* __restrict__ M,
    const float* __restrict__ cube,
    float* __restrict__ out) {
  const int bq = blockIdx.x;
  const int b = bq >> 2, q = bq & 3;
  const int tid = threadIdx.x;
  const int lane = tid & 63;
  const int wv = tid >> 6;

  __shared__ __align__(16) uint8_t shbuf[53408];
  float4*   sv4    = (float4*)shbuf;
  float4*   sp4    = (float4*)(shbuf + 12448);
  float*    fbuf   = (float*)(shbuf + 28832);
  uint32_t* hist   = (uint32_t*)(shbuf + 45216);
  uint64_t* cand   = (uint64_t*)(shbuf + 47264);
  float*    candrv = (float*)(shbuf + 51360);
  __shared__ uint32_t wt[8], offs[8];
  __shared__ uint32_t swt[16], soffs[16];
  __shared__ float sh_minv[6], sh_c[3], sh_hb[3];
  __shared__ uint32_t sh_bstar, sh_above;
  __shared__ float red[16];

  if (tid == 0) {
    const float* m = M + (size_t)b * 9;
    float m00=m[0], m01=m[1], m02=m[2];
    float m10=m[3], m11=m[4], m12=m[5];
    float m20=m[6], m21=m[7], m22=m[8];
    float c00 = m11*m22 - m12*m21;
    float c10 = m12*m20 - m10*m22;
    float c20 = m10*m21 - m11*m20;
    float det = m00*c00 + m01*c10 + m02*c20;
    float id = 1.0f / det;
    sh_minv[0] = c00 * id;
    sh_minv[1] = (m02*m21 - m01*m22) * id;
    sh_minv[2] = (m01*m12 - m02*m11) * id;
    sh_minv[3] = c10 * id;
    sh_minv[4] = (m00*m22 - m02*m20) * id;
    sh_minv[5] = (m02*m10 - m00*m12) * id;
    sh_c[0] = center[b*3+0]; sh_c[1] = center[b*3+1]; sh_c[2] = center[b*3+2];
    sh_hb[0] = cube[b*3+0]*0.5f; sh_hb[1] = cube[b*3+1]*0.5f; sh_hb[2] = cube[b*3+2]*0.5f;
  }
  if (tid < 512) hist[tid] = 0u;

  const float* vb = verts + (size_t)b * NV * 3;
  for (int v = tid; v < NV; v += 1024) {
    float x = vb[v*3], y = vb[v*3+1], z = vb[v*3+2];
    float4 t;
    t.x = -2.0f*x; t.y = -2.0f*y; t.z = -2.0f*z; t.w = x*x + y*y + z*z;
    sv4[v] = t;
  }

  uint32_t uv[16];
  float    rvv[16];
  const float4* rb4 = real4 + (size_t)b * (NPIX / 4);
#pragma unroll
  for (int e4 = 0; e4 < 4; ++e4) {
    float4 im = rb4[e4 * 1024 + tid];
    uint32_t base = (uint32_t)(b * NPIX + e4 * 4096) + (uint32_t)(tid << 2);
    rvv[e4*4+0] = im.x; rvv[e4*4+1] = im.y; rvv[e4*4+2] = im.z; rvv[e4*4+3] = im.w;
    uv[e4*4+0] = (im.x <= 0.99f) ? ((threefry_bits(base + 0u) >> 9) + 1u) : 0u;
    uv[e4*4+1] = (im.y <= 0.99f) ? ((threefry_bits(base + 1u) >> 9) + 1u) : 0u;
    uv[e4*4+2] = (im.z <= 0.99f) ? ((threefry_bits(base + 2u) >> 9) + 1u) : 0u;
    uv[e4*4+3] = (im.w <= 0.99f) ? ((threefry_bits(base + 3u) >> 9) + 1u) : 0u;
  }
  __syncthreads();

#pragma unroll
  for (int e = 0; e < 16; ++e)
    if (uv[e]) atomicAdd(&hist[(uv[e] - 1u) >> 14], 1u);
  __syncthreads();

  uint32_t cnt = 0, sfx = 0;
  if (tid < 512) {
    cnt = hist[tid];
    sfx = cnt;
#pragma unroll
    for (int off = 1; off < 64; off <<= 1) {
      uint32_t u = __shfl_down(sfx, off, 64);
      if (lane + off < 64) sfx += u;
    }
    if (lane == 0) wt[wv] = sfx;
  }
  __syncthreads();
  if (tid < 8) {
    uint32_t t = wt[tid], s = t;
#pragma unroll
    for (int off = 1; off < 8; off <<= 1) {
      uint32_t u = __shfl_down(s, off, 64);
      if (tid + off < 8) s += u;
    }
    offs[tid] = s - t;
  }
  __syncthreads();
  if (tid < 512) {
    uint32_t tot = sfx + offs[wv];
    uint32_t above = tot - cnt;
    if (tot >= SAMPLE && above < SAMPLE && cnt > 0) {
      sh_bstar = (uint32_t)tid;
      sh_above = above;
    }
  }
  __syncthreads();
  const int bstar = (int)sh_bstar;
  const uint32_t above = sh_above;
  const uint32_t kneed = SAMPLE - above;

  auto emit = [&](int p, float depth01, uint32_t slot) {
    int i = p >> 7, j = p & 127;
    float tj = (2.0f * (float)j) / 127.0f - 1.0f;
    float ti = (2.0f * (float)i) / 127.0f - 1.0f;
    float u0 = (tj + 1.0f) * 64.0f;
    float u1 = (ti + 1.0f) * 64.0f;
    float d  = depth01 * sh_hb[2] + sh_c[2];
    float w0 = sh_minv[0]*u0 + sh_minv[1]*u1 + sh_minv[2];
    float w1 = sh_minv[3]*u0 + sh_minv[4]*u1 + sh_minv[5];
    float x = (w0 - 320.0f) * d / 588.03f;
    float y = (w1 - 240.0f) * d / 587.07f;
    float ox = (x - sh_c[0]) / sh_hb[0];
    float oy = (y - sh_c[1]) / sh_hb[1];
    float oz = (d - sh_c[2]) / sh_hb[2];
    float4 t;
    t.x = -2.0f*ox; t.y = -2.0f*oy; t.z = -2.0f*oz;
    t.w = ox*ox + oy*oy + oz*oz;
    sp4[slot] = t;
  };

  uint32_t ch = 0, ce = 0;
#pragma unroll
  for (int e = 0; e < 16; ++e) {
    int bk = uv[e] ? (int)((uv[e] - 1u) >> 14) : -1;
    ch += (bk > bstar) ? 1u : 0u;
    ce += (bk == bstar) ? 1u : 0u;
  }
  uint32_t htot, etot;
  uint32_t hoff = blockExclScan1024(ch, swt, soffs, &htot);
  uint32_t eoff = blockExclScan1024(ce, swt, soffs, &etot);

  {
    uint32_t h = hoff, eo = eoff;
#pragma unroll
    for (int e = 0; e < 16; ++e) {
      uint32_t v = uv[e];
      int bk = v ? (int)((v - 1u) >> 14) : -1;
      int p = (e >> 2) * 4096 + (tid << 2) + (e & 3);
      if (bk > bstar) {
        emit(p, rvv[e], h++);
      } else if (bk == bstar) {
        if (eo < 512u) {
          cand[eo] = ((uint64_t)v << 14) | (uint64_t)(16383 - p);
          candrv[eo] = rvv[e];
        }
        eo++;
      }
    }
  }
  __syncthreads();

  uint32_t c = etot; if (c > 512u) c = 512u;
  uint32_t selbit = 0; uint64_t ki = 0;
  if (tid < (int)c) {
    ki = cand[tid];
    uint32_t rank = 0;
    for (uint32_t j2 = 0; j2 < c; ++j2) rank += (cand[j2] > ki) ? 1u : 0u;
    selbit = (rank < kneed) ? 1u : 0u;
  }
  uint32_t stot;
  uint32_t soff2 = blockExclScan1024(selbit, swt, soffs, &stot);
  if (selbit) {
    int p = 16383 - (int)(ki & 0x3FFFull);
    emit(p, candrv[tid], above + soff2);
  }
  __syncthreads();

  float val = 0.0f;
  const int sub = tid & 63;
  const int seg16 = tid >> 6;

  {
    float px[4], py[4], pz[4], mnA[4];
#pragma unroll
    for (int j = 0; j < 4; ++j) {
      float4 sp = sp4[q * 256 + j * 64 + sub];
      px[j] = -0.5f * sp.x; py[j] = -0.5f * sp.y; pz[j] = -0.5f * sp.z;
      mnA[j] = INFINITY;
    }
    int vs = seg16 * 49, ve = vs + 49; if (ve > NV) ve = NV;
    for (int v = vs; v < ve; ++v) {
      float4 vv = sv4[v];
#pragma unroll
      for (int j = 0; j < 4; ++j) {
        float t = fmaf(pz[j], vv.z, fmaf(py[j], vv.y, fmaf(px[j], vv.x, vv.w)));
        mnA[j] = fminf(mnA[j], t);
      }
    }
#pragma unroll
    for (int j = 0; j < 4; ++j) fbuf[seg16 * 256 + j * 64 + sub] = mnA[j];
  }
  __syncthreads();
  if (tid < 256) {
    float m = fbuf[tid];
#pragma unroll
    for (int s2 = 1; s2 < 16; ++s2) m = fminf(m, fbuf[s2 * 256 + tid]);
    val += (m + sp4[q * 256 + tid].w) * A_SCALE;
  }
  __syncthreads();

  {
    const int vbase = q * 195;
    int nsl = NV - vbase; if (nsl > 195) nsl = 195;
    float vx[4], vy[4], vz[4], mnB[4];
#pragma unroll
    for (int j = 0; j < 4; ++j) {
      int vloc = j * 64 + sub;
      int vi = (vloc < nsl) ? (vbase + vloc) : 0;
      float4 sv = sv4[vi];
      vx[j] = -0.5f * sv.x; vy[j] = -0.5f * sv.y; vz[j] = -0.5f * sv.z;
      mnB[j] = INFINITY;
    }
    int is = seg16 * 64;
    for (int i = 0; i < 64; ++i) {
      float4 pp = sp4[is + i];
#pragma unroll
      for (int j = 0; j < 4; ++j) {
        float t = fmaf(vz[j], pp.z, fmaf(vy[j], pp.y, fmaf(vx[j], pp.x, pp.w)));
        mnB[j] = fminf(mnB[j], t);
      }
    }
#pragma unroll
    for (int j = 0; j < 4; ++j) fbuf[seg16 * 256 + j * 64 + sub] = mnB[j];
  }
  __syncthreads();
  {
    const int vbase = q * 195;
    int nsl = NV - vbase; if (nsl > 195) nsl = 195;
    if (tid < nsl) {
      float m = fbuf[tid];
#pragma unroll
      for (int s2 = 1; s2 < 16; ++s2) m = fminf(m, fbuf[s2 * 256 + tid]);
      val += (m + sv4[vbase + tid].w) * B_SCALE;
    }
  }

  float r = waveReduceSum(val);
  if (lane == 0) red[wv] = r;
  __syncthreads();
  if (tid == 0) {
    float s = 0.0f;
#pragma unroll
    for (int i = 0; i < 16; ++i) s += red[i];
    atomicAdd(out, s);
  }
}

extern "C" void kernel_launch(void* const* d_in, const int* in_sizes, int n_in,
                              void* d_out, int out_size, void* d_ws, size_t ws_size,
                              hipStream_t stream) {
  const float* real   = (const float*)d_in[0];
  // d_in[1] = synth (unused), d_in[3] = faces (unused)
  const float* verts  = (const float*)d_in[2];
  const float* center = (const float*)d_in[4];
  const float* M      = (const float*)d_in[5];
  const float* cube   = (const float*)d_in[6];
  float* out = (float*)d_out;

  if (ws_size >= (size_t)WS_NEEDED) {
    uint8_t* w = (uint8_t*)d_ws;
    uint32_t* ubits = (uint32_t*)(w + WS_UBITS);
    uint32_t* histg = (uint32_t*)(w + WS_HISTG);
    score_kernel<<<dim3(BATCH * 4), dim3(1024), 0, stream>>>(
        (const float4*)real, ubits, histg, out);
    chamsel_kernel<<<dim3(BATCH * 4), dim3(1024), 0, stream>>>(
        real, verts, center, M, cube, ubits, histg, out);
  } else {
    hipMemsetAsync(out, 0, sizeof(float), stream);
    mega_kernel<<<dim3(BATCH * 4), dim3(1024), 0, stream>>>(
        (const float4*)real, verts, center, M, cube, out);
  }
}